// Round 12
// baseline (3710.527 us; speedup 1.0000x reference)
//
#include <hip/hip_runtime.h>
#include <stdint.h>

#define SEQ 197
#define NB 32
#define NH 12
#define NTOK (SEQ*NB)      // 6304
#define MPAD 6400          // 50 * 128, 25 * 256
#define NPATCH 6272        // 49 * 128

typedef unsigned short u16;
typedef unsigned int u32;
typedef __attribute__((ext_vector_type(8))) short bv8;    // 8 x bf16 (4 VGPR)
typedef __attribute__((ext_vector_type(4))) float f32x4;

__device__ __forceinline__ u16 f2bf(float f){
  u32 u = __float_as_uint(f);
  u = (u + 0x7fffu + ((u >> 16) & 1u)) >> 16;   // RNE
  return (u16)u;
}
__device__ __forceinline__ float bf2f(u16 h){ return __uint_as_float(((u32)h) << 16); }

#if defined(__has_builtin)
#if __has_builtin(__builtin_amdgcn_global_load_lds)
#define HAS_GLLDS 1
#endif
#endif

// async global->LDS, 16B per lane. LDS dest is wave-uniform base + lane*16.
__device__ __forceinline__ void gl_lds16(const void* g, void* l){
#ifdef HAS_GLLDS
  __builtin_amdgcn_global_load_lds(
      (const __attribute__((address_space(1))) void*)(uintptr_t)g,
      (__attribute__((address_space(3))) void*)(u32)(uintptr_t)l, 16, 0, 0);
#else
  int lane = threadIdx.x & 63;
  uint4 v = *(const uint4*)((const char*)g);
  *(uint4*)((char*)l + lane*16) = v;
#endif
}

// block-wide double reduction (blockDim.x == 256)
__device__ __forceinline__ void red2(float& a, float& b){
  #pragma unroll
  for (int o = 32; o > 0; o >>= 1){ a += __shfl_down(a, o); b += __shfl_down(b, o); }
  __shared__ float red[8];
  int w = threadIdx.x >> 6, ln = threadIdx.x & 63;
  if (ln == 0){ red[w] = a; red[4 + w] = b; }
  __syncthreads();
  a = red[0] + red[1] + red[2] + red[3];
  b = red[4] + red[5] + red[6] + red[7];
}

// ---------------- f32 -> bf16 weight conversion ----------------
__global__ __launch_bounds__(256) void cvt_k(const float* __restrict__ src, u16* __restrict__ dst, int n4){
  int i = blockIdx.x * 256 + threadIdx.x;
  if (i >= n4) return;
  float4 f = ((const float4*)src)[i];
  u32 lo = (u32)f2bf(f.x) | ((u32)f2bf(f.y) << 16);
  u32 hi = (u32)f2bf(f.z) | ((u32)f2bf(f.w) << 16);
  ((uint2*)dst)[i] = make_uint2(lo, hi);
}

// ---------------- im2col: image [32,3,224,224] -> A [6272, 768] bf16 ----------------
__global__ __launch_bounds__(256) void im2col_k(const float* __restrict__ img, u16* __restrict__ Ap){
  int gid = blockIdx.x * 256 + threadIdx.x;
  int row = gid / 768, k = gid - row * 768;
  int b = row / 196, p = row - b * 196;
  int pr = p / 14, pc = p - pr * 14;
  int c = k >> 8, r = k & 255;
  int ph = r >> 4, pw = r & 15;
  size_t src = ((size_t)(b * 3 + c) * 224 + (pr * 16 + ph)) * 224 + (pc * 16 + pw);
  Ap[gid] = f2bf(img[src]);
}

// ------------- GEMM 128x128 serial, r6-EXACT: patchify + out -------------
template<int EPI>
__global__ __launch_bounds__(256, 2)
void gemm_sw(const u16* __restrict__ A, const u16* __restrict__ Bw,
             const float* __restrict__ bias, float* __restrict__ Cf,
             u16* __restrict__ Cb, int N, int K, int Mreal,
             int RM, int RN, int tmT, int tnT)
{
  __shared__ __align__(16) u16 sA[128 * 64];
  __shared__ __align__(16) u16 sB[128 * 64];
  const int xcd = blockIdx.x & 7, pos = blockIdx.x >> 3;
  const int xm = xcd >> 1, xn = xcd & 1;
  const int tm = xm * RM + pos / RN;
  const int tn = xn * RN + pos % RN;
  if (tm >= tmT || tn >= tnT) return;

  const int tid = threadIdx.x;
  const int lane = tid & 63, wave = tid >> 6;
  const int wm = wave >> 1, wn = wave & 1;
  const int lr = lane & 15, g = lane >> 4, g4 = g * 4;
  const int KT = K >> 6;

  const int srow = lane >> 3;
  const int sch = (lane & 7) ^ srow;
  const u16* aB[4]; const u16* bB[4];
  u16* lA[4]; u16* lB[4];
  #pragma unroll
  for (int j = 0; j < 4; j++){
    int rr = wave * 32 + j * 8;
    aB[j] = A  + (size_t)(tm * 128 + rr + srow) * K + sch * 8;
    bB[j] = Bw + (size_t)(tn * 128 + rr + srow) * K + sch * 8;
    lA[j] = sA + rr * 64;
    lB[j] = sB + rr * 64;
  }

  f32x4 acc[4][4] = {};

  for (int kt = 0; kt < KT; ++kt){
    __syncthreads();
    #pragma unroll
    for (int j = 0; j < 4; j++) gl_lds16(aB[j] + (size_t)kt * 64, lA[j]);
    #pragma unroll
    for (int j = 0; j < 4; j++) gl_lds16(bB[j] + (size_t)kt * 64, lB[j]);
    __syncthreads();
    #pragma unroll
    for (int kk = 0; kk < 2; kk++){
      bv8 af[4], bf[4];
      #pragma unroll
      for (int mi = 0; mi < 4; mi++){
        int row = wm * 64 + mi * 16 + lr;
        af[mi] = *(const bv8*)((const char*)sA + row * 128 + ((kk * 64 + g * 16) ^ ((row & 7) << 4)));
      }
      #pragma unroll
      for (int ni = 0; ni < 4; ni++){
        int row = wn * 64 + ni * 16 + lr;
        bf[ni] = *(const bv8*)((const char*)sB + row * 128 + ((kk * 64 + g * 16) ^ ((row & 7) << 4)));
      }
      #pragma unroll
      for (int mi = 0; mi < 4; mi++)
        #pragma unroll
        for (int ni = 0; ni < 4; ni++)
          acc[mi][ni] = __builtin_amdgcn_mfma_f32_16x16x32_bf16(af[mi], bf[ni], acc[mi][ni], 0, 0, 0);
    }
  }

  #pragma unroll
  for (int ni = 0; ni < 4; ni++){
    int col = tn * 128 + wn * 64 + ni * 16 + lr;
    float bvs = (EPI != 0) ? bias[col] : 0.f;
    #pragma unroll
    for (int mi = 0; mi < 4; mi++){
      int row0 = tm * 128 + wm * 64 + mi * 16 + g4;
      #pragma unroll
      for (int j = 0; j < 4; j++){
        int row = row0 + j;
        if (row < Mreal){
          float v = acc[mi][ni][j] + bvs;
          size_t idx = (size_t)row * N + col;
          if (EPI == 0) Cf[idx] = v;
          else          Cf[idx] += v;
        }
      }
    }
  }
}

// ------------- GEMM 256x128 serial "tall tile" (new): qkv + fc -------------
// Same inner loop / schedule / per-wave registers as gemm_sw; 8 waves (512 thr),
// wave grid 4x2 of 64x64 tiles. Staged bytes per FLOP drop 1.33x (1/85 vs 1/64)
// and waves/CU double (2 blocks x 8 waves). LDS 48KB. bf16 out via 2-pass bounce.
// EPI: 1 +bias -> bf16 | 3 +bias GELU -> bf16
template<int EPI>
__global__ __launch_bounds__(512, 2)
void gemm_t2(const u16* __restrict__ A, const u16* __restrict__ Bw,
             const float* __restrict__ bias, u16* __restrict__ Cb,
             int N, int K, int RM, int RN, int tmT, int tnT)
{
  __shared__ __align__(16) u16 sA[256 * 64];   // 32KB
  __shared__ __align__(16) u16 sB[128 * 64];   // 16KB
  const int xcd = blockIdx.x & 7, pos = blockIdx.x >> 3;
  const int xm = xcd >> 1, xn = xcd & 1;
  const int tm = xm * RM + pos / RN;
  const int tn = xn * RN + pos % RN;
  if (tm >= tmT || tn >= tnT) return;

  const int tid = threadIdx.x;
  const int lane = tid & 63, wave = tid >> 6;   // 8 waves
  const int wm = wave >> 1, wn = wave & 1;      // 4 x 2 grid of 64x64 wave tiles
  const int lr = lane & 15, g = lane >> 4, g4 = g * 4;
  const int KT = K >> 6;

  const int srow = lane >> 3;
  const int sch = (lane & 7) ^ srow;
  const u16* aB[4]; const u16* bB[2];
  u16* lA[4]; u16* lB[2];
  #pragma unroll
  for (int j = 0; j < 4; j++){                  // A: 8 waves x 32 rows = 256
    int rr = wave * 32 + j * 8;
    aB[j] = A + (size_t)(tm * 256 + rr + srow) * K + sch * 8;
    lA[j] = sA + rr * 64;
  }
  #pragma unroll
  for (int j = 0; j < 2; j++){                  // B: 8 waves x 16 rows = 128
    int rr = wave * 16 + j * 8;
    bB[j] = Bw + (size_t)(tn * 128 + rr + srow) * K + sch * 8;
    lB[j] = sB + rr * 64;
  }

  f32x4 acc[4][4] = {};

  for (int kt = 0; kt < KT; ++kt){
    __syncthreads();
    #pragma unroll
    for (int j = 0; j < 4; j++) gl_lds16(aB[j] + (size_t)kt * 64, lA[j]);
    #pragma unroll
    for (int j = 0; j < 2; j++) gl_lds16(bB[j] + (size_t)kt * 64, lB[j]);
    __syncthreads();
    #pragma unroll
    for (int kk = 0; kk < 2; kk++){
      bv8 af[4], bf[4];
      #pragma unroll
      for (int mi = 0; mi < 4; mi++){
        int row = wm * 64 + mi * 16 + lr;       // 0..255
        af[mi] = *(const bv8*)((const char*)sA + row * 128 + ((kk * 64 + g * 16) ^ ((row & 7) << 4)));
      }
      #pragma unroll
      for (int ni = 0; ni < 4; ni++){
        int row = wn * 64 + ni * 16 + lr;       // 0..127
        bf[ni] = *(const bv8*)((const char*)sB + row * 128 + ((kk * 64 + g * 16) ^ ((row & 7) << 4)));
      }
      #pragma unroll
      for (int mi = 0; mi < 4; mi++)
        #pragma unroll
        for (int ni = 0; ni < 4; ni++)
          acc[mi][ni] = __builtin_amdgcn_mfma_f32_16x16x32_bf16(af[mi], bf[ni], acc[mi][ni], 0, 0, 0);
    }
  }

  // epilogue: 2 passes of 128 rows through sA (128 x 256B = 32KB), coalesced stores.
  // Output rows land in padded (MPAD-row) ws buffers -> no row guard needed.
  #pragma unroll
  for (int p = 0; p < 2; p++){
    __syncthreads();
    if ((wm >> 1) == p){
      #pragma unroll
      for (int mi = 0; mi < 4; mi++){
        #pragma unroll
        for (int ni = 0; ni < 4; ni++){
          int bcol = wn * 64 + ni * 16 + lr;
          float bvs = bias[tn * 128 + bcol];
          #pragma unroll
          for (int j = 0; j < 4; j++){
            int brow = (wm & 1) * 64 + mi * 16 + g4 + j;   // 0..127 within pass
            float v = acc[mi][ni][j] + bvs;
            if (EPI == 3) v = 0.5f * v * (1.f + erff(v * 0.70710678118654752f));
            *(u16*)((char*)sA + brow * 256 + ((bcol * 2) ^ ((brow & 7) << 4))) = f2bf(v);
          }
        }
      }
    }
    __syncthreads();
    #pragma unroll
    for (int c = 0; c < 4; c++){
      int off = c * 8192 + tid * 16;
      int row = off >> 8;                        // 0..127
      int colb = off & 255;
      uint4 v = *(const uint4*)((const char*)sA + row * 256 + (colb ^ ((row & 7) << 4)));
      *(uint4*)((char*)(Cb + (size_t)(tm * 256 + p * 128 + row) * N + tn * 128) + colb) = v;
    }
  }
}

// ------------- GEMM 128x128 2-phase counted-vmcnt, r7-EXACT: pr (KT=48) -------------
template<int EPI>
__global__ __launch_bounds__(256, 2)
void gemm_2ph(const u16* __restrict__ A, const u16* __restrict__ Bw,
              const float* __restrict__ bias, float* __restrict__ Cf,
              u16* __restrict__ Cb, int N, int K, int Mreal,
              int RM, int RN, int tmT, int tnT)
{
  __shared__ __align__(16) u16 sA0[128 * 64];
  __shared__ __align__(16) u16 sB0[128 * 64];
  __shared__ __align__(16) u16 sA1[128 * 64];
  __shared__ __align__(16) u16 sB1[128 * 64];
  const int xcd = blockIdx.x & 7, pos = blockIdx.x >> 3;
  const int xm = xcd >> 1, xn = xcd & 1;
  const int tm = xm * RM + pos / RN;
  const int tn = xn * RN + pos % RN;
  if (tm >= tmT || tn >= tnT) return;

  const int tid = threadIdx.x;
  const int lane = tid & 63, wave = tid >> 6;
  const int wm = wave >> 1, wn = wave & 1;
  const int lr = lane & 15, g = lane >> 4, g4 = g * 4;
  const int KT = K >> 6;

  const int srow = lane >> 3;
  const int sch = (lane & 7) ^ srow;
  const u16* aB[4]; const u16* bB[4];
  #pragma unroll
  for (int j = 0; j < 4; j++){
    int rr = wave * 32 + j * 8;
    aB[j] = A  + (size_t)(tm * 128 + rr + srow) * K + sch * 8;
    bB[j] = Bw + (size_t)(tn * 128 + rr + srow) * K + sch * 8;
  }

  f32x4 acc[4][4] = {};

  auto stage = [&](int kt, u16* dA, u16* dB){
    #pragma unroll
    for (int j = 0; j < 4; j++)
      gl_lds16(aB[j] + (size_t)kt * 64, dA + (wave * 32 + j * 8) * 64);
    #pragma unroll
    for (int j = 0; j < 4; j++)
      gl_lds16(bB[j] + (size_t)kt * 64, dB + (wave * 32 + j * 8) * 64);
  };
  auto tile = [&](const u16* sA, const u16* sB, u16* dA, u16* dB, int ktNext, bool doStage, bool last){
    if (last) asm volatile("s_waitcnt vmcnt(0)" ::: "memory");
    else      asm volatile("s_waitcnt vmcnt(8)" ::: "memory");
    __builtin_amdgcn_s_barrier();
    bv8 af[4][2], bf[4][2];
    #pragma unroll
    for (int mi = 0; mi < 4; mi++){
      int row = wm * 64 + mi * 16 + lr;
      #pragma unroll
      for (int kk = 0; kk < 2; kk++)
        af[mi][kk] = *(const bv8*)((const char*)sA + row * 128 + ((kk * 64 + g * 16) ^ ((row & 7) << 4)));
    }
    #pragma unroll
    for (int ni = 0; ni < 4; ni++){
      int row = wn * 64 + ni * 16 + lr;
      #pragma unroll
      for (int kk = 0; kk < 2; kk++)
        bf[ni][kk] = *(const bv8*)((const char*)sB + row * 128 + ((kk * 64 + g * 16) ^ ((row & 7) << 4)));
    }
    asm volatile("s_waitcnt lgkmcnt(0)" ::: "memory");
    __builtin_amdgcn_s_barrier();
    if (doStage) stage(ktNext, dA, dB);
    __builtin_amdgcn_s_setprio(1);
    #pragma unroll
    for (int kk = 0; kk < 2; kk++)
      #pragma unroll
      for (int mi = 0; mi < 4; mi++)
        #pragma unroll
        for (int ni = 0; ni < 4; ni++)
          acc[mi][ni] = __builtin_amdgcn_mfma_f32_16x16x32_bf16(af[mi][kk], bf[ni][kk], acc[mi][ni], 0, 0, 0);
    __builtin_amdgcn_s_setprio(0);
  };

  stage(0, sA0, sB0);
  stage(1, sA1, sB1);
  int t = 0;
  for (; t + 2 < KT; t += 2){
    tile(sA0, sB0, sA0, sB0, t + 2, true,  false);
    tile(sA1, sB1, sA1, sB1, t + 3, true,  false);
  }
  tile(sA0, sB0, sA0, sB0, 0, false, false);
  tile(sA1, sB1, sA1, sB1, 0, false, true);

  #pragma unroll
  for (int ni = 0; ni < 4; ni++){
    int col = tn * 128 + wn * 64 + ni * 16 + lr;
    float bvs = (EPI != 0) ? bias[col] : 0.f;
    #pragma unroll
    for (int mi = 0; mi < 4; mi++){
      int row0 = tm * 128 + wm * 64 + mi * 16 + g4;
      #pragma unroll
      for (int j = 0; j < 4; j++){
        int row = row0 + j;
        if (row < Mreal){
          float v = acc[mi][ni][j] + bvs;
          size_t idx = (size_t)row * N + col;
          if (EPI == 0) Cf[idx] = v;
          else          Cf[idx] += v;
        }
      }
    }
  }
}

// ---------------- MFMA flash attention: 2 blocks per (b,h), 4 waves x 32 Q-rows ----------------
__global__ __launch_bounds__(256, 2) void attn_k(const u16* __restrict__ qkv, u16* __restrict__ o_out){
  __shared__ __align__(16) u16 sK[256 * 64];
  __shared__ __align__(16) u16 sVT[64 * 256];
  __shared__ __align__(16) u16 sP[4 * 32 * 64];
  const int bh2 = blockIdx.x;
  const int bh = bh2 >> 1, half = bh2 & 1;
  const int b = bh / NH, h = bh - b * NH;
  const int tid = threadIdx.x;
  const int lane = tid & 63, wave = tid >> 6;
  const int lr = lane & 15, g = lane >> 4;
  const int g4 = g * 4;
  const int wb = half * 128 + wave * 32;
  const u16* kbase = qkv + (size_t)b * SEQ * 2304 + h * 64 + 768;
  const u16* vbase = kbase + 768;

  bv8 qf[2][2];
  #pragma unroll
  for (int qt = 0; qt < 2; qt++){
    int q = wb + qt * 16 + lr; if (q > 196) q = 196;
    const u16* qr = qkv + (size_t)(b * SEQ + q) * 2304 + h * 64;
    #pragma unroll
    for (int kc = 0; kc < 2; kc++)
      qf[qt][kc] = *(const bv8*)(qr + kc * 32 + g * 8);
  }

  for (int i = tid; i < 197 * 32; i += 256){
    int r = i >> 5, c = i & 31;
    u32 kv_ = *(const u32*)(kbase + (size_t)r * 2304 + c * 2);
    *(u32*)((char*)sK + ((r * 128 + c * 4) ^ ((r & 7) << 4))) = kv_;
    u32 vv = *(const u32*)(vbase + (size_t)r * 2304 + c * 2);
    int hd0 = c * 2, hd1 = c * 2 + 1;
    *(u16*)((char*)sVT + ((hd0 * 512 + r * 2) ^ ((hd0 & 7) << 4))) = (u16)(vv & 0xffff);
    *(u16*)((char*)sVT + ((hd1 * 512 + r * 2) ^ ((hd1 & 7) << 4))) = (u16)(vv >> 16);
  }
  for (int i = tid; i < 59 * 32; i += 256){
    int r = 197 + (i >> 5), c = i & 31;
    *(u32*)((char*)sK + (r * 128 + c * 4)) = 0;
  }
  for (int i = tid; i < 59 * 64; i += 256){
    int kv = 197 + (i >> 6), hd = i & 63;
    *(u16*)((char*)sVT + ((hd * 512 + kv * 2) ^ ((hd & 7) << 4))) = 0;
  }
  __syncthreads();

  f32x4 acc_o[2][4] = {};
  float m_[2] = {-1e30f, -1e30f};
  float l_[2] = {0.f, 0.f};
  u16* sPw = sP + wave * 2048;

  for (int ch = 0; ch < 4; ++ch){
    f32x4 st[4][2] = {};
    #pragma unroll
    for (int kc = 0; kc < 2; kc++){
      bv8 kf[4];
      #pragma unroll
      for (int kvt = 0; kvt < 4; kvt++){
        int row = ch * 64 + kvt * 16 + lr;
        kf[kvt] = *(const bv8*)((const char*)sK + ((row * 128 + kc * 64 + g * 16) ^ ((row & 7) << 4)));
      }
      #pragma unroll
      for (int kvt = 0; kvt < 4; kvt++)
        #pragma unroll
        for (int qt = 0; qt < 2; qt++)
          st[kvt][qt] = __builtin_amdgcn_mfma_f32_16x16x32_bf16(kf[kvt], qf[qt][kc], st[kvt][qt], 0, 0, 0);
    }
    float fac[2];
    #pragma unroll
    for (int qt = 0; qt < 2; qt++){
      float mx = -1e30f;
      #pragma unroll
      for (int kvt = 0; kvt < 4; kvt++)
        #pragma unroll
        for (int j = 0; j < 4; j++){
          int kvg = ch * 64 + kvt * 16 + g4 + j;
          float s = st[kvt][qt][j] * 0.125f;
          s = (kvg < 197) ? s : -1e30f;
          st[kvt][qt][j] = s;
          mx = fmaxf(mx, s);
        }
      mx = fmaxf(mx, __shfl_xor(mx, 16));
      mx = fmaxf(mx, __shfl_xor(mx, 32));
      float nm = fmaxf(m_[qt], mx);
      fac[qt] = __expf(m_[qt] - nm);
      m_[qt] = nm;
      float ls = 0.f;
      #pragma unroll
      for (int kvt = 0; kvt < 4; kvt++)
        #pragma unroll
        for (int j = 0; j < 4; j++){
          float p = __expf(st[kvt][qt][j] - nm);
          st[kvt][qt][j] = p;
          ls += p;
        }
      ls += __shfl_xor(ls, 16);
      ls += __shfl_xor(ls, 32);
      l_[qt] = l_[qt] * fac[qt] + ls;
    }
    #pragma unroll
    for (int qt = 0; qt < 2; qt++)
      #pragma unroll
      for (int j = 0; j < 4; j++){
        float fj = __shfl(fac[qt], (lane & 48) | (g4 + j));
        #pragma unroll
        for (int nt = 0; nt < 4; nt++) acc_o[qt][nt][j] *= fj;
      }
    #pragma unroll
    for (int qt = 0; qt < 2; qt++){
      int row = qt * 16 + lr;
      #pragma unroll
      for (int kvt = 0; kvt < 4; kvt++){
        uint2 pk;
        pk.x = (u32)f2bf(st[kvt][qt][0]) | ((u32)f2bf(st[kvt][qt][1]) << 16);
        pk.y = (u32)f2bf(st[kvt][qt][2]) | ((u32)f2bf(st[kvt][qt][3]) << 16);
        *(uint2*)((char*)sPw + ((row * 128 + kvt * 32 + g * 8) ^ ((row & 7) << 4))) = pk;
      }
    }
    #pragma unroll
    for (int kc = 0; kc < 2; kc++){
      bv8 pa[2], vb[4];
      #pragma unroll
      for (int qt = 0; qt < 2; qt++){
        int row = qt * 16 + lr;
        pa[qt] = *(const bv8*)((const char*)sPw + ((row * 128 + kc * 64 + g * 16) ^ ((row & 7) << 4)));
      }
      #pragma unroll
      for (int nt = 0; nt < 4; nt++){
        int hd = nt * 16 + lr;
        vb[nt] = *(const bv8*)((const char*)sVT + ((hd * 512 + ch * 128 + kc * 64 + g * 16) ^ ((hd & 7) << 4)));
      }
      #pragma unroll
      for (int qt = 0; qt < 2; qt++)
        #pragma unroll
        for (int nt = 0; nt < 4; nt++)
          acc_o[qt][nt] = __builtin_amdgcn_mfma_f32_16x16x32_bf16(pa[qt], vb[nt], acc_o[qt][nt], 0, 0, 0);
    }
  }

  #pragma unroll
  for (int qt = 0; qt < 2; qt++)
    #pragma unroll
    for (int j = 0; j < 4; j++){
      float lj = __shfl(l_[qt], (lane & 48) | (g4 + j));
      float rl = 1.f / lj;
      int row = wb + qt * 16 + g4 + j;
      if (row < 197){
        u16* dst = o_out + (size_t)(b * SEQ + row) * 768 + h * 64;
        #pragma unroll
        for (int nt = 0; nt < 4; nt++)
          dst[nt * 16 + lr] = f2bf(acc_o[qt][nt][j] * rl);
      }
    }
}

// ---------------- embed (cls + patches + pos) then ln_pre -> x f32 ----------------
__global__ __launch_bounds__(256) void embed_ln_k(const float* __restrict__ patch, const float* __restrict__ cls,
    const float* __restrict__ pos, const float* __restrict__ w, const float* __restrict__ bb, float* __restrict__ x)
{
  int t = blockIdx.x;
  int b = t / SEQ, s = t - b * SEQ;
  int tid = threadIdx.x;
  float v[3];
  #pragma unroll
  for (int i = 0; i < 3; i++){
    int d = tid + i * 256;
    float base = (s == 0) ? cls[d] : patch[(size_t)(b * 196 + s - 1) * 768 + d];
    v[i] = base + pos[s * 768 + d];
  }
  float sm = v[0] + v[1] + v[2];
  float sq = v[0]*v[0] + v[1]*v[1] + v[2]*v[2];
  red2(sm, sq);
  float m = sm * (1.f / 768.f);
  float rs = rsqrtf(sq * (1.f / 768.f) - m * m + 1e-5f);
  #pragma unroll
  for (int i = 0; i < 3; i++){
    int d = tid + i * 256;
    x[(size_t)t * 768 + d] = (v[i] - m) * rs * w[d] + bb[d];
  }
}

// ---------------- LN (f32 in) -> bf16 out ----------------
__global__ __launch_bounds__(256) void ln_bf16_k(const float* __restrict__ x, const float* __restrict__ w,
    const float* __restrict__ bb, u16* __restrict__ h)
{
  int t = blockIdx.x, tid = threadIdx.x;
  const float* xr = x + (size_t)t * 768;
  float v[3];
  #pragma unroll
  for (int i = 0; i < 3; i++) v[i] = xr[tid + i * 256];
  float sm = v[0] + v[1] + v[2];
  float sq = v[0]*v[0] + v[1]*v[1] + v[2]*v[2];
  red2(sm, sq);
  float m = sm * (1.f / 768.f);
  float rs = rsqrtf(sq * (1.f / 768.f) - m * m + 1e-5f);
  #pragma unroll
  for (int i = 0; i < 3; i++){
    int d = tid + i * 256;
    h[(size_t)t * 768 + d] = f2bf((v[i] - m) * rs * w[d] + bb[d]);
  }
}

// ---------------- ln_post on cls tokens -> f32 ----------------
__global__ __launch_bounds__(256) void ln_cls_k(const float* __restrict__ x, const float* __restrict__ w,
    const float* __restrict__ bb, float* __restrict__ cls)
{
  int b = blockIdx.x, tid = threadIdx.x;
  const float* xr = x + (size_t)b * SEQ * 768;
  float v[3];
  #pragma unroll
  for (int i = 0; i < 3; i++) v[i] = xr[tid + i * 256];
  float sm = v[0] + v[1] + v[2];
  float sq = v[0]*v[0] + v[1]*v[1] + v[2]*v[2];
  red2(sm, sq);
  float m = sm * (1.f / 768.f);
  float rs = rsqrtf(sq * (1.f / 768.f) - m * m + 1e-5f);
  #pragma unroll
  for (int i = 0; i < 3; i++){
    int d = tid + i * 256;
    cls[b * 768 + d] = (v[i] - m) * rs * w[d] + bb[d];
  }
}

// ---------------- final projection [32,768] @ [768,512] ----------------
__global__ __launch_bounds__(256) void proj_k(const float* __restrict__ cls, const float* __restrict__ P,
                                              float* __restrict__ feats){
  int gid = blockIdx.x * 256 + threadIdx.x;
  int b = gid >> 9, e = gid & 511;
  const float* c = cls + b * 768;
  float a0 = 0, a1 = 0, a2 = 0, a3 = 0;
  for (int d = 0; d < 768; d += 4){
    a0 += c[d]     * P[(size_t)d * 512 + e];
    a1 += c[d + 1] * P[(size_t)(d + 1) * 512 + e];
    a2 += c[d + 2] * P[(size_t)(d + 2) * 512 + e];
    a3 += c[d + 3] * P[(size_t)(d + 3) * 512 + e];
  }
  feats[gid] = (a0 + a1) + (a2 + a3);
}

// ---------------- L2 normalize ----------------
__global__ __launch_bounds__(256) void norm_k(const float* __restrict__ feats, float* __restrict__ out){
  int b = blockIdx.x, tid = threadIdx.x;
  float v0 = feats[b * 512 + tid], v1 = feats[b * 512 + 256 + tid];
  float sq = v0 * v0 + v1 * v1, dummy = 0.f;
  red2(sq, dummy);
  float inv = 1.f / sqrtf(sq);
  out[b * 512 + tid] = v0 * inv;
  out[b * 512 + 256 + tid] = v1 * inv;
}

extern "C" void kernel_launch(void* const* d_in, const int* in_sizes, int n_in,
                              void* d_out, int out_size, void* d_ws, size_t ws_size,
                              hipStream_t stream)
{
  const float* image   = (const float*)d_in[0];
  const float* conv_w  = (const float*)d_in[1];
  const float* cls_emb = (const float*)d_in[2];
  const float* pos_emb = (const float*)d_in[3];
  const float* lnprew  = (const float*)d_in[4];
  const float* lnpreb  = (const float*)d_in[5];
  const float* ln1w    = (const float*)d_in[6];
  const float* ln1b    = (const float*)d_in[7];
  const float* qkvw    = (const float*)d_in[8];
  const float* qkvb    = (const float*)d_in[9];
  const float* outw    = (const float*)d_in[10];
  const float* outb    = (const float*)d_in[11];
  const float* ln2w    = (const float*)d_in[12];
  const float* ln2b    = (const float*)d_in[13];
  const float* fcw     = (const float*)d_in[14];
  const float* fcb     = (const float*)d_in[15];
  const float* prw     = (const float*)d_in[16];
  const float* prb     = (const float*)d_in[17];
  const float* lnpostw = (const float*)d_in[18];
  const float* lnpostb = (const float*)d_in[19];
  const float* proj    = (const float*)d_in[20];
  (void)in_sizes; (void)n_in; (void)out_size;

  const size_t QW = (size_t)2304 * 768, OW = (size_t)768 * 768;
  const size_t FW = (size_t)3072 * 768, PW = (size_t)768 * 3072;
  const size_t CW = (size_t)768 * 768;

  char* p = (char*)d_ws;
  auto alloc = [&](size_t bytes)->char*{ char* r = p; p += (bytes + 255) & ~(size_t)255; return r; };
  float* x     = (float*)alloc((size_t)MPAD * 768 * 4);
  u16*   h     = (u16*)  alloc((size_t)MPAD * 768 * 2);
  u16*   qkvB  = (u16*)  alloc((size_t)MPAD * 2304 * 2);
  u16*   attno = (u16*)  alloc((size_t)MPAD * 768 * 2);
  u16*   ffh   = (u16*)  alloc((size_t)MPAD * 3072 * 2);
  u16*   Ap    = (u16*)  alloc((size_t)NPATCH * 768 * 2);
  float* patch = (float*)alloc((size_t)NPATCH * 768 * 4);
  float* clsb  = (float*)alloc((size_t)32 * 768 * 4);
  float* feats = (float*)alloc((size_t)32 * 512 * 4);
  u16*   cwb   = (u16*)  alloc(CW * 2);
  size_t base_used = (size_t)(p - (char*)d_ws);
  size_t full_need = (QW + OW + FW + PW) * 12 * 2;
  bool full = (base_used + full_need + 4096 <= ws_size);

  u16 *wq = nullptr, *wo = nullptr, *wf = nullptr, *wp = nullptr;
  u16 *sq_ = nullptr, *so_ = nullptr, *sf_ = nullptr, *sp_ = nullptr;
  if (full){
    wq = (u16*)alloc(QW * 12 * 2); wo = (u16*)alloc(OW * 12 * 2);
    wf = (u16*)alloc(FW * 12 * 2); wp = (u16*)alloc(PW * 12 * 2);
  } else {
    sq_ = (u16*)alloc(QW * 2); so_ = (u16*)alloc(OW * 2);
    sf_ = (u16*)alloc(FW * 2); sp_ = (u16*)alloc(PW * 2);
  }
  if ((size_t)(p - (char*)d_ws) > ws_size) return;

  { int n4 = (int)(CW / 4); cvt_k<<<(n4 + 255) / 256, 256, 0, stream>>>(conv_w, cwb, n4); }
  if (full){
    int n4;
    n4 = (int)(QW * 12 / 4); cvt_k<<<(n4 + 255) / 256, 256, 0, stream>>>(qkvw, wq, n4);
    n4 = (int)(OW * 12 / 4); cvt_k<<<(n4 + 255) / 256, 256, 0, stream>>>(outw, wo, n4);
    n4 = (int)(FW * 12 / 4); cvt_k<<<(n4 + 255) / 256, 256, 0, stream>>>(fcw,  wf, n4);
    n4 = (int)(PW * 12 / 4); cvt_k<<<(n4 + 255) / 256, 256, 0, stream>>>(prw,  wp, n4);
  }

  im2col_k<<<(NPATCH * 768) / 256, 256, 0, stream>>>(image, Ap);
  gemm_sw<0><<<8 * 13 * 3, 256, 0, stream>>>(Ap, cwb, nullptr, patch, nullptr, 768, 768, NPATCH, 13, 3, 49, 6);
  embed_ln_k<<<NTOK, 256, 0, stream>>>(patch, cls_emb, pos_emb, lnprew, lnpreb, x);

  for (int l = 0; l < 12; l++){
    const u16 *WQ, *WO, *WF, *WP;
    if (full){
      WQ = wq + (size_t)l * QW; WO = wo + (size_t)l * OW;
      WF = wf + (size_t)l * FW; WP = wp + (size_t)l * PW;
    } else {
      int n4;
      n4 = (int)(QW / 4); cvt_k<<<(n4 + 255) / 256, 256, 0, stream>>>(qkvw + (size_t)l * QW, sq_, n4);
      n4 = (int)(OW / 4); cvt_k<<<(n4 + 255) / 256, 256, 0, stream>>>(outw + (size_t)l * OW, so_, n4);
      n4 = (int)(FW / 4); cvt_k<<<(n4 + 255) / 256, 256, 0, stream>>>(fcw  + (size_t)l * FW, sf_, n4);
      n4 = (int)(PW / 4); cvt_k<<<(n4 + 255) / 256, 256, 0, stream>>>(prw  + (size_t)l * PW, sp_, n4);
      WQ = sq_; WO = so_; WF = sf_; WP = sp_;
    }
    ln_bf16_k<<<NTOK, 256, 0, stream>>>(x, ln1w + l * 768, ln1b + l * 768, h);
    // qkv: 256x128 tall tile, grid 25x18 -> RM=7, RN=9
    gemm_t2<1><<<8 * 7 * 9, 512, 0, stream>>>(h, WQ, qkvb + l * 2304, qkvB, 2304, 768, 7, 9, 25, 18);
    attn_k<<<NB * NH * 2, 256, 0, stream>>>(qkvB, attno);
    // out: serial 128^2 (KT=12), 50x6 -> RM=13, RN=3
    gemm_sw<2><<<8 * 13 * 3, 256, 0, stream>>>(attno, WO, outb + l * 768, x, nullptr, 768, 768, NTOK, 13, 3, 50, 6);
    ln_bf16_k<<<NTOK, 256, 0, stream>>>(x, ln2w + l * 768, ln2b + l * 768, h);
    // fc: 256x128 tall tile, grid 25x24 -> RM=7, RN=12
    gemm_t2<3><<<8 * 7 * 12, 512, 0, stream>>>(h, WF, fcb + l * 3072, ffh, 3072, 768, 7, 12, 25, 24);
    // pr: r7 2ph (KT=48), 50x6 -> RM=13, RN=3
    gemm_2ph<2><<<8 * 13 * 3, 256, 0, stream>>>(ffh, WP, prb + l * 768, x, nullptr, 768, 3072, NTOK, 13, 3, 50, 6);
  }

  ln_cls_k<<<NB, 256, 0, stream>>>(x, lnpostw, lnpostb, clsb);
  proj_k<<<(NB * 512) / 256, 256, 0, stream>>>(clsb, proj, feats);
  norm_k<<<NB, 256, 0, stream>>>(feats, (float*)d_out);
}

// Round 13
// 2792.160 us; speedup vs baseline: 1.3289x; 1.3289x over previous
//
#include <hip/hip_runtime.h>
#include <stdint.h>

#define SEQ 197
#define NB 32
#define NH 12
#define NTOK (SEQ*NB)      // 6304
#define MPAD 6400          // 50 * 128
#define NPATCH 6272        // 49 * 128

typedef unsigned short u16;
typedef unsigned int u32;
typedef __attribute__((ext_vector_type(8))) short bv8;    // 8 x bf16 (4 VGPR)
typedef __attribute__((ext_vector_type(4))) float f32x4;

__device__ __forceinline__ u16 f2bf(float f){
  u32 u = __float_as_uint(f);
  u = (u + 0x7fffu + ((u >> 16) & 1u)) >> 16;   // RNE
  return (u16)u;
}
__device__ __forceinline__ float bf2f(u16 h){ return __uint_as_float(((u32)h) << 16); }

#if defined(__has_builtin)
#if __has_builtin(__builtin_amdgcn_global_load_lds)
#define HAS_GLLDS 1
#endif
#endif

// async global->LDS, 16B per lane. LDS dest is wave-uniform base + lane*16.
__device__ __forceinline__ void gl_lds16(const void* g, void* l){
#ifdef HAS_GLLDS
  __builtin_amdgcn_global_load_lds(
      (const __attribute__((address_space(1))) void*)(uintptr_t)g,
      (__attribute__((address_space(3))) void*)(u32)(uintptr_t)l, 16, 0, 0);
#else
  int lane = threadIdx.x & 63;
  uint4 v = *(const uint4*)((const char*)g);
  *(uint4*)((char*)l + lane*16) = v;
#endif
}

// block-wide double reduction (blockDim.x == 256)
__device__ __forceinline__ void red2(float& a, float& b){
  #pragma unroll
  for (int o = 32; o > 0; o >>= 1){ a += __shfl_down(a, o); b += __shfl_down(b, o); }
  __shared__ float red[8];
  int w = threadIdx.x >> 6, ln = threadIdx.x & 63;
  if (ln == 0){ red[w] = a; red[4 + w] = b; }
  __syncthreads();
  a = red[0] + red[1] + red[2] + red[3];
  b = red[4] + red[5] + red[6] + red[7];
}

// ---------------- f32 -> bf16 weight conversion ----------------
__global__ __launch_bounds__(256) void cvt_k(const float* __restrict__ src, u16* __restrict__ dst, int n4){
  int i = blockIdx.x * 256 + threadIdx.x;
  if (i >= n4) return;
  float4 f = ((const float4*)src)[i];
  u32 lo = (u32)f2bf(f.x) | ((u32)f2bf(f.y) << 16);
  u32 hi = (u32)f2bf(f.z) | ((u32)f2bf(f.w) << 16);
  ((uint2*)dst)[i] = make_uint2(lo, hi);
}

// ---------------- im2col: image [32,3,224,224] -> A [6272, 768] bf16 ----------------
__global__ __launch_bounds__(256) void im2col_k(const float* __restrict__ img, u16* __restrict__ Ap){
  int gid = blockIdx.x * 256 + threadIdx.x;
  int row = gid / 768, k = gid - row * 768;
  int b = row / 196, p = row - b * 196;
  int pr = p / 14, pc = p - pr * 14;
  int c = k >> 8, r = k & 255;
  int ph = r >> 4, pw = r & 15;
  size_t src = ((size_t)(b * 3 + c) * 224 + (pr * 16 + ph)) * 224 + (pc * 16 + pw);
  Ap[gid] = f2bf(img[src]);
}

// ------------- GEMM 128x128 serial, r6-EXACT (best for KT=12) -------------
// EPI: 0 plain f32 | 1 +bias -> bf16 (LDS bounce) | 2 +bias, += Cf | 3 +bias GELU -> bf16 (LDS bounce)
template<int EPI>
__global__ __launch_bounds__(256, 2)
void gemm_sw(const u16* __restrict__ A, const u16* __restrict__ Bw,
             const float* __restrict__ bias, float* __restrict__ Cf,
             u16* __restrict__ Cb, int N, int K, int Mreal,
             int RM, int RN, int tmT, int tnT)
{
  __shared__ __align__(16) u16 sA[128 * 64];
  __shared__ __align__(16) u16 sB[128 * 64];
  const int xcd = blockIdx.x & 7, pos = blockIdx.x >> 3;
  const int xm = xcd >> 1, xn = xcd & 1;
  const int tm = xm * RM + pos / RN;
  const int tn = xn * RN + pos % RN;
  if (tm >= tmT || tn >= tnT) return;

  const int tid = threadIdx.x;
  const int lane = tid & 63, wave = tid >> 6;
  const int wm = wave >> 1, wn = wave & 1;      // 2x2 waves of 64x64
  const int lr = lane & 15, g = lane >> 4, g4 = g * 4;
  const int KT = K >> 6;

  const int srow = lane >> 3;
  const int sch = (lane & 7) ^ srow;
  const u16* aB[4]; const u16* bB[4];
  u16* lA[4]; u16* lB[4];
  #pragma unroll
  for (int j = 0; j < 4; j++){
    int rr = wave * 32 + j * 8;
    aB[j] = A  + (size_t)(tm * 128 + rr + srow) * K + sch * 8;
    bB[j] = Bw + (size_t)(tn * 128 + rr + srow) * K + sch * 8;
    lA[j] = sA + rr * 64;
    lB[j] = sB + rr * 64;
  }

  f32x4 acc[4][4] = {};

  for (int kt = 0; kt < KT; ++kt){
    __syncthreads();
    #pragma unroll
    for (int j = 0; j < 4; j++) gl_lds16(aB[j] + (size_t)kt * 64, lA[j]);
    #pragma unroll
    for (int j = 0; j < 4; j++) gl_lds16(bB[j] + (size_t)kt * 64, lB[j]);
    __syncthreads();
    #pragma unroll
    for (int kk = 0; kk < 2; kk++){
      bv8 af[4], bf[4];
      #pragma unroll
      for (int mi = 0; mi < 4; mi++){
        int row = wm * 64 + mi * 16 + lr;
        af[mi] = *(const bv8*)((const char*)sA + row * 128 + ((kk * 64 + g * 16) ^ ((row & 7) << 4)));
      }
      #pragma unroll
      for (int ni = 0; ni < 4; ni++){
        int row = wn * 64 + ni * 16 + lr;
        bf[ni] = *(const bv8*)((const char*)sB + row * 128 + ((kk * 64 + g * 16) ^ ((row & 7) << 4)));
      }
      #pragma unroll
      for (int mi = 0; mi < 4; mi++)
        #pragma unroll
        for (int ni = 0; ni < 4; ni++)
          acc[mi][ni] = __builtin_amdgcn_mfma_f32_16x16x32_bf16(af[mi], bf[ni], acc[mi][ni], 0, 0, 0);
    }
  }

  if (EPI == 1 || EPI == 3){
    __syncthreads();
    u16* sC = sA;
    #pragma unroll
    for (int mi = 0; mi < 4; mi++){
      #pragma unroll
      for (int ni = 0; ni < 4; ni++){
        int bcol = wn * 64 + ni * 16 + lr;
        float bvs = bias[tn * 128 + bcol];
        #pragma unroll
        for (int j = 0; j < 4; j++){
          int brow = wm * 64 + mi * 16 + g4 + j;
          float v = acc[mi][ni][j] + bvs;
          if (EPI == 3) v = 0.5f * v * (1.f + erff(v * 0.70710678118654752f));
          *(u16*)((char*)sC + brow * 256 + ((bcol * 2) ^ ((brow & 7) << 4))) = f2bf(v);
        }
      }
    }
    __syncthreads();
    #pragma unroll
    for (int c = 0; c < 8; c++){
      int off = c * 4096 + tid * 16;
      int row = off >> 8;
      int colb = off & 255;
      uint4 v = *(const uint4*)((const char*)sC + row * 256 + (colb ^ ((row & 7) << 4)));
      *(uint4*)((char*)(Cb + (size_t)(tm * 128 + row) * N + tn * 128) + colb) = v;
    }
  } else {
    #pragma unroll
    for (int ni = 0; ni < 4; ni++){
      int col = tn * 128 + wn * 64 + ni * 16 + lr;
      float bvs = (EPI != 0) ? bias[col] : 0.f;
      #pragma unroll
      for (int mi = 0; mi < 4; mi++){
        int row0 = tm * 128 + wm * 64 + mi * 16 + g4;
        #pragma unroll
        for (int j = 0; j < 4; j++){
          int row = row0 + j;
          if (row < Mreal){
            float v = acc[mi][ni][j] + bvs;
            size_t idx = (size_t)row * N + col;
            if (EPI == 0) Cf[idx] = v;
            else          Cf[idx] += v;
          }
        }
      }
    }
  }
}

// ------------- GEMM 128x128 2-phase counted-vmcnt, r7-EXACT: pr (KT=48) -------------
template<int EPI>
__global__ __launch_bounds__(256, 2)
void gemm_2ph(const u16* __restrict__ A, const u16* __restrict__ Bw,
              const float* __restrict__ bias, float* __restrict__ Cf,
              u16* __restrict__ Cb, int N, int K, int Mreal,
              int RM, int RN, int tmT, int tnT)
{
  __shared__ __align__(16) u16 sA0[128 * 64];
  __shared__ __align__(16) u16 sB0[128 * 64];
  __shared__ __align__(16) u16 sA1[128 * 64];
  __shared__ __align__(16) u16 sB1[128 * 64];
  const int xcd = blockIdx.x & 7, pos = blockIdx.x >> 3;
  const int xm = xcd >> 1, xn = xcd & 1;
  const int tm = xm * RM + pos / RN;
  const int tn = xn * RN + pos % RN;
  if (tm >= tmT || tn >= tnT) return;

  const int tid = threadIdx.x;
  const int lane = tid & 63, wave = tid >> 6;
  const int wm = wave >> 1, wn = wave & 1;
  const int lr = lane & 15, g = lane >> 4, g4 = g * 4;
  const int KT = K >> 6;

  const int srow = lane >> 3;
  const int sch = (lane & 7) ^ srow;
  const u16* aB[4]; const u16* bB[4];
  #pragma unroll
  for (int j = 0; j < 4; j++){
    int rr = wave * 32 + j * 8;
    aB[j] = A  + (size_t)(tm * 128 + rr + srow) * K + sch * 8;
    bB[j] = Bw + (size_t)(tn * 128 + rr + srow) * K + sch * 8;
  }

  f32x4 acc[4][4] = {};

  auto stage = [&](int kt, u16* dA, u16* dB){
    #pragma unroll
    for (int j = 0; j < 4; j++)
      gl_lds16(aB[j] + (size_t)kt * 64, dA + (wave * 32 + j * 8) * 64);
    #pragma unroll
    for (int j = 0; j < 4; j++)
      gl_lds16(bB[j] + (size_t)kt * 64, dB + (wave * 32 + j * 8) * 64);
  };
  auto tile = [&](const u16* sA, const u16* sB, u16* dA, u16* dB, int ktNext, bool doStage, bool last){
    if (last) asm volatile("s_waitcnt vmcnt(0)" ::: "memory");
    else      asm volatile("s_waitcnt vmcnt(8)" ::: "memory");
    __builtin_amdgcn_s_barrier();
    bv8 af[4][2], bf[4][2];
    #pragma unroll
    for (int mi = 0; mi < 4; mi++){
      int row = wm * 64 + mi * 16 + lr;
      #pragma unroll
      for (int kk = 0; kk < 2; kk++)
        af[mi][kk] = *(const bv8*)((const char*)sA + row * 128 + ((kk * 64 + g * 16) ^ ((row & 7) << 4)));
    }
    #pragma unroll
    for (int ni = 0; ni < 4; ni++){
      int row = wn * 64 + ni * 16 + lr;
      #pragma unroll
      for (int kk = 0; kk < 2; kk++)
        bf[ni][kk] = *(const bv8*)((const char*)sB + row * 128 + ((kk * 64 + g * 16) ^ ((row & 7) << 4)));
    }
    asm volatile("s_waitcnt lgkmcnt(0)" ::: "memory");
    __builtin_amdgcn_s_barrier();
    if (doStage) stage(ktNext, dA, dB);
    __builtin_amdgcn_s_setprio(1);
    #pragma unroll
    for (int kk = 0; kk < 2; kk++)
      #pragma unroll
      for (int mi = 0; mi < 4; mi++)
        #pragma unroll
        for (int ni = 0; ni < 4; ni++)
          acc[mi][ni] = __builtin_amdgcn_mfma_f32_16x16x32_bf16(af[mi][kk], bf[ni][kk], acc[mi][ni], 0, 0, 0);
    __builtin_amdgcn_s_setprio(0);
  };

  stage(0, sA0, sB0);
  stage(1, sA1, sB1);
  int t = 0;
  for (; t + 2 < KT; t += 2){
    tile(sA0, sB0, sA0, sB0, t + 2, true,  false);
    tile(sA1, sB1, sA1, sB1, t + 3, true,  false);
  }
  tile(sA0, sB0, sA0, sB0, 0, false, false);
  tile(sA1, sB1, sA1, sB1, 0, false, true);

  #pragma unroll
  for (int ni = 0; ni < 4; ni++){
    int col = tn * 128 + wn * 64 + ni * 16 + lr;
    float bvs = (EPI != 0) ? bias[col] : 0.f;
    #pragma unroll
    for (int mi = 0; mi < 4; mi++){
      int row0 = tm * 128 + wm * 64 + mi * 16 + g4;
      #pragma unroll
      for (int j = 0; j < 4; j++){
        int row = row0 + j;
        if (row < Mreal){
          float v = acc[mi][ni][j] + bvs;
          size_t idx = (size_t)row * N + col;
          if (EPI == 0) Cf[idx] = v;
          else          Cf[idx] += v;
        }
      }
    }
  }
}

// ---------------- MFMA flash attention: 2 blocks per (b,h), 4 waves x 32 Q-rows ----------------
// r10 structure; K-staging widened to 8B/lane (uint2) — XOR swizzle is 16B-granular
// so 8B-aligned chunks remain contiguous under the swizzle.
__global__ __launch_bounds__(256, 2) void attn_k(const u16* __restrict__ qkv, u16* __restrict__ o_out){
  __shared__ __align__(16) u16 sK[256 * 64];
  __shared__ __align__(16) u16 sVT[64 * 256];
  __shared__ __align__(16) u16 sP[4 * 32 * 64];
  const int bh2 = blockIdx.x;
  const int bh = bh2 >> 1, half = bh2 & 1;
  const int b = bh / NH, h = bh - b * NH;
  const int tid = threadIdx.x;
  const int lane = tid & 63, wave = tid >> 6;
  const int lr = lane & 15, g = lane >> 4;
  const int g4 = g * 4;
  const int wb = half * 128 + wave * 32;
  const u16* kbase = qkv + (size_t)b * SEQ * 2304 + h * 64 + 768;
  const u16* vbase = kbase + 768;

  bv8 qf[2][2];
  #pragma unroll
  for (int qt = 0; qt < 2; qt++){
    int q = wb + qt * 16 + lr; if (q > 196) q = 196;
    const u16* qr = qkv + (size_t)(b * SEQ + q) * 2304 + h * 64;
    #pragma unroll
    for (int kc = 0; kc < 2; kc++)
      qf[qt][kc] = *(const bv8*)(qr + kc * 32 + g * 8);
  }

  // K: 8B chunks (16 per row); V: 8B load, u16 transpose-scatter
  for (int i = tid; i < 197 * 16; i += 256){
    int r = i >> 4, c = i & 15;
    uint2 kv2 = *(const uint2*)(kbase + (size_t)r * 2304 + c * 4);
    *(uint2*)((char*)sK + ((r * 128 + c * 8) ^ ((r & 7) << 4))) = kv2;
    uint2 vv2 = *(const uint2*)(vbase + (size_t)r * 2304 + c * 4);
    #pragma unroll
    for (int e = 0; e < 4; e++){
      int hd = c * 4 + e;
      u16 val = (e < 2) ? (u16)(vv2.x >> (e * 16)) : (u16)(vv2.y >> ((e - 2) * 16));
      *(u16*)((char*)sVT + ((hd * 512 + r * 2) ^ ((hd & 7) << 4))) = val;
    }
  }
  for (int i = tid; i < 59 * 32; i += 256){
    int r = 197 + (i >> 5), c = i & 31;
    *(u32*)((char*)sK + (r * 128 + c * 4)) = 0;
  }
  for (int i = tid; i < 59 * 64; i += 256){
    int kv = 197 + (i >> 6), hd = i & 63;
    *(u16*)((char*)sVT + ((hd * 512 + kv * 2) ^ ((hd & 7) << 4))) = 0;
  }
  __syncthreads();

  f32x4 acc_o[2][4] = {};
  float m_[2] = {-1e30f, -1e30f};
  float l_[2] = {0.f, 0.f};
  u16* sPw = sP + wave * 2048;

  for (int ch = 0; ch < 4; ++ch){
    f32x4 st[4][2] = {};
    #pragma unroll
    for (int kc = 0; kc < 2; kc++){
      bv8 kf[4];
      #pragma unroll
      for (int kvt = 0; kvt < 4; kvt++){
        int row = ch * 64 + kvt * 16 + lr;
        kf[kvt] = *(const bv8*)((const char*)sK + ((row * 128 + kc * 64 + g * 16) ^ ((row & 7) << 4)));
      }
      #pragma unroll
      for (int kvt = 0; kvt < 4; kvt++)
        #pragma unroll
        for (int qt = 0; qt < 2; qt++)
          st[kvt][qt] = __builtin_amdgcn_mfma_f32_16x16x32_bf16(kf[kvt], qf[qt][kc], st[kvt][qt], 0, 0, 0);
    }
    float fac[2];
    #pragma unroll
    for (int qt = 0; qt < 2; qt++){
      float mx = -1e30f;
      #pragma unroll
      for (int kvt = 0; kvt < 4; kvt++)
        #pragma unroll
        for (int j = 0; j < 4; j++){
          int kvg = ch * 64 + kvt * 16 + g4 + j;
          float s = st[kvt][qt][j] * 0.125f;
          s = (kvg < 197) ? s : -1e30f;
          st[kvt][qt][j] = s;
          mx = fmaxf(mx, s);
        }
      mx = fmaxf(mx, __shfl_xor(mx, 16));
      mx = fmaxf(mx, __shfl_xor(mx, 32));
      float nm = fmaxf(m_[qt], mx);
      fac[qt] = __expf(m_[qt] - nm);
      m_[qt] = nm;
      float ls = 0.f;
      #pragma unroll
      for (int kvt = 0; kvt < 4; kvt++)
        #pragma unroll
        for (int j = 0; j < 4; j++){
          float p = __expf(st[kvt][qt][j] - nm);
          st[kvt][qt][j] = p;
          ls += p;
        }
      ls += __shfl_xor(ls, 16);
      ls += __shfl_xor(ls, 32);
      l_[qt] = l_[qt] * fac[qt] + ls;
    }
    #pragma unroll
    for (int qt = 0; qt < 2; qt++)
      #pragma unroll
      for (int j = 0; j < 4; j++){
        float fj = __shfl(fac[qt], (lane & 48) | (g4 + j));
        #pragma unroll
        for (int nt = 0; nt < 4; nt++) acc_o[qt][nt][j] *= fj;
      }
    #pragma unroll
    for (int qt = 0; qt < 2; qt++){
      int row = qt * 16 + lr;
      #pragma unroll
      for (int kvt = 0; kvt < 4; kvt++){
        uint2 pk;
        pk.x = (u32)f2bf(st[kvt][qt][0]) | ((u32)f2bf(st[kvt][qt][1]) << 16);
        pk.y = (u32)f2bf(st[kvt][qt][2]) | ((u32)f2bf(st[kvt][qt][3]) << 16);
        *(uint2*)((char*)sPw + ((row * 128 + kvt * 32 + g * 8) ^ ((row & 7) << 4))) = pk;
      }
    }
    #pragma unroll
    for (int kc = 0; kc < 2; kc++){
      bv8 pa[2], vb[4];
      #pragma unroll
      for (int qt = 0; qt < 2; qt++){
        int row = qt * 16 + lr;
        pa[qt] = *(const bv8*)((const char*)sPw + ((row * 128 + kc * 64 + g * 16) ^ ((row & 7) << 4)));
      }
      #pragma unroll
      for (int nt = 0; nt < 4; nt++){
        int hd = nt * 16 + lr;
        vb[nt] = *(const bv8*)((const char*)sVT + ((hd * 512 + ch * 128 + kc * 64 + g * 16) ^ ((hd & 7) << 4)));
      }
      #pragma unroll
      for (int qt = 0; qt < 2; qt++)
        #pragma unroll
        for (int nt = 0; nt < 4; nt++)
          acc_o[qt][nt] = __builtin_amdgcn_mfma_f32_16x16x32_bf16(pa[qt], vb[nt], acc_o[qt][nt], 0, 0, 0);
    }
  }

  #pragma unroll
  for (int qt = 0; qt < 2; qt++)
    #pragma unroll
    for (int j = 0; j < 4; j++){
      float lj = __shfl(l_[qt], (lane & 48) | (g4 + j));
      float rl = 1.f / lj;
      int row = wb + qt * 16 + g4 + j;
      if (row < 197){
        u16* dst = o_out + (size_t)(b * SEQ + row) * 768 + h * 64;
        #pragma unroll
        for (int nt = 0; nt < 4; nt++)
          dst[nt * 16 + lr] = f2bf(acc_o[qt][nt][j] * rl);
      }
    }
}

// ---------------- embed (cls + patches + pos) then ln_pre -> x f32 ----------------
__global__ __launch_bounds__(256) void embed_ln_k(const float* __restrict__ patch, const float* __restrict__ cls,
    const float* __restrict__ pos, const float* __restrict__ w, const float* __restrict__ bb, float* __restrict__ x)
{
  int t = blockIdx.x;
  int b = t / SEQ, s = t - b * SEQ;
  int tid = threadIdx.x;
  float v[3];
  #pragma unroll
  for (int i = 0; i < 3; i++){
    int d = tid + i * 256;
    float base = (s == 0) ? cls[d] : patch[(size_t)(b * 196 + s - 1) * 768 + d];
    v[i] = base + pos[s * 768 + d];
  }
  float sm = v[0] + v[1] + v[2];
  float sq = v[0]*v[0] + v[1]*v[1] + v[2]*v[2];
  red2(sm, sq);
  float m = sm * (1.f / 768.f);
  float rs = rsqrtf(sq * (1.f / 768.f) - m * m + 1e-5f);
  #pragma unroll
  for (int i = 0; i < 3; i++){
    int d = tid + i * 256;
    x[(size_t)t * 768 + d] = (v[i] - m) * rs * w[d] + bb[d];
  }
}

// ---------------- LN (f32 in) -> bf16 out ----------------
__global__ __launch_bounds__(256) void ln_bf16_k(const float* __restrict__ x, const float* __restrict__ w,
    const float* __restrict__ bb, u16* __restrict__ h)
{
  int t = blockIdx.x, tid = threadIdx.x;
  const float* xr = x + (size_t)t * 768;
  float v[3];
  #pragma unroll
  for (int i = 0; i < 3; i++) v[i] = xr[tid + i * 256];
  float sm = v[0] + v[1] + v[2];
  float sq = v[0]*v[0] + v[1]*v[1] + v[2]*v[2];
  red2(sm, sq);
  float m = sm * (1.f / 768.f);
  float rs = rsqrtf(sq * (1.f / 768.f) - m * m + 1e-5f);
  #pragma unroll
  for (int i = 0; i < 3; i++){
    int d = tid + i * 256;
    h[(size_t)t * 768 + d] = f2bf((v[i] - m) * rs * w[d] + bb[d]);
  }
}

// ---------------- ln_post on cls tokens -> f32 ----------------
__global__ __launch_bounds__(256) void ln_cls_k(const float* __restrict__ x, const float* __restrict__ w,
    const float* __restrict__ bb, float* __restrict__ cls)
{
  int b = blockIdx.x, tid = threadIdx.x;
  const float* xr = x + (size_t)b * SEQ * 768;
  float v[3];
  #pragma unroll
  for (int i = 0; i < 3; i++) v[i] = xr[tid + i * 256];
  float sm = v[0] + v[1] + v[2];
  float sq = v[0]*v[0] + v[1]*v[1] + v[2]*v[2];
  red2(sm, sq);
  float m = sm * (1.f / 768.f);
  float rs = rsqrtf(sq * (1.f / 768.f) - m * m + 1e-5f);
  #pragma unroll
  for (int i = 0; i < 3; i++){
    int d = tid + i * 256;
    cls[b * 768 + d] = (v[i] - m) * rs * w[d] + bb[d];
  }
}

// ---------------- final projection [32,768] @ [768,512] ----------------
__global__ __launch_bounds__(256) void proj_k(const float* __restrict__ cls, const float* __restrict__ P,
                                              float* __restrict__ feats){
  int gid = blockIdx.x * 256 + threadIdx.x;
  int b = gid >> 9, e = gid & 511;
  const float* c = cls + b * 768;
  float a0 = 0, a1 = 0, a2 = 0, a3 = 0;
  for (int d = 0; d < 768; d += 4){
    a0 += c[d]     * P[(size_t)d * 512 + e];
    a1 += c[d + 1] * P[(size_t)(d + 1) * 512 + e];
    a2 += c[d + 2] * P[(size_t)(d + 2) * 512 + e];
    a3 += c[d + 3] * P[(size_t)(d + 3) * 512 + e];
  }
  feats[gid] = (a0 + a1) + (a2 + a3);
}

// ---------------- L2 normalize ----------------
__global__ __launch_bounds__(256) void norm_k(const float* __restrict__ feats, float* __restrict__ out){
  int b = blockIdx.x, tid = threadIdx.x;
  float v0 = feats[b * 512 + tid], v1 = feats[b * 512 + 256 + tid];
  float sq = v0 * v0 + v1 * v1, dummy = 0.f;
  red2(sq, dummy);
  float inv = 1.f / sqrtf(sq);
  out[b * 512 + tid] = v0 * inv;
  out[b * 512 + 256 + tid] = v1 * inv;
}

extern "C" void kernel_launch(void* const* d_in, const int* in_sizes, int n_in,
                              void* d_out, int out_size, void* d_ws, size_t ws_size,
                              hipStream_t stream)
{
  const float* image   = (const float*)d_in[0];
  const float* conv_w  = (const float*)d_in[1];
  const float* cls_emb = (const float*)d_in[2];
  const float* pos_emb = (const float*)d_in[3];
  const float* lnprew  = (const float*)d_in[4];
  const float* lnpreb  = (const float*)d_in[5];
  const float* ln1w    = (const float*)d_in[6];
  const float* ln1b    = (const float*)d_in[7];
  const float* qkvw    = (const float*)d_in[8];
  const float* qkvb    = (const float*)d_in[9];
  const float* outw    = (const float*)d_in[10];
  const float* outb    = (const float*)d_in[11];
  const float* ln2w    = (const float*)d_in[12];
  const float* ln2b    = (const float*)d_in[13];
  const float* fcw     = (const float*)d_in[14];
  const float* fcb     = (const float*)d_in[15];
  const float* prw     = (const float*)d_in[16];
  const float* prb     = (const float*)d_in[17];
  const float* lnpostw = (const float*)d_in[18];
  const float* lnpostb = (const float*)d_in[19];
  const float* proj    = (const float*)d_in[20];
  (void)in_sizes; (void)n_in; (void)out_size;

  const size_t QW = (size_t)2304 * 768, OW = (size_t)768 * 768;
  const size_t FW = (size_t)3072 * 768, PW = (size_t)768 * 3072;
  const size_t CW = (size_t)768 * 768;

  char* p = (char*)d_ws;
  auto alloc = [&](size_t bytes)->char*{ char* r = p; p += (bytes + 255) & ~(size_t)255; return r; };
  float* x     = (float*)alloc((size_t)MPAD * 768 * 4);
  u16*   h     = (u16*)  alloc((size_t)MPAD * 768 * 2);
  u16*   qkvB  = (u16*)  alloc((size_t)MPAD * 2304 * 2);
  u16*   attno = (u16*)  alloc((size_t)MPAD * 768 * 2);
  u16*   ffh   = (u16*)  alloc((size_t)MPAD * 3072 * 2);
  u16*   Ap    = (u16*)  alloc((size_t)NPATCH * 768 * 2);
  float* patch = (float*)alloc((size_t)NPATCH * 768 * 4);
  float* clsb  = (float*)alloc((size_t)32 * 768 * 4);
  float* feats = (float*)alloc((size_t)32 * 512 * 4);
  u16*   cwb   = (u16*)  alloc(CW * 2);
  size_t base_used = (size_t)(p - (char*)d_ws);
  size_t full_need = (QW + OW + FW + PW) * 12 * 2;
  bool full = (base_used + full_need + 4096 <= ws_size);

  u16 *wq = nullptr, *wo = nullptr, *wf = nullptr, *wp = nullptr;
  u16 *sq_ = nullptr, *so_ = nullptr, *sf_ = nullptr, *sp_ = nullptr;
  if (full){
    wq = (u16*)alloc(QW * 12 * 2); wo = (u16*)alloc(OW * 12 * 2);
    wf = (u16*)alloc(FW * 12 * 2); wp = (u16*)alloc(PW * 12 * 2);
  } else {
    sq_ = (u16*)alloc(QW * 2); so_ = (u16*)alloc(OW * 2);
    sf_ = (u16*)alloc(FW * 2); sp_ = (u16*)alloc(PW * 2);
  }
  if ((size_t)(p - (char*)d_ws) > ws_size) return;

  { int n4 = (int)(CW / 4); cvt_k<<<(n4 + 255) / 256, 256, 0, stream>>>(conv_w, cwb, n4); }
  if (full){
    int n4;
    n4 = (int)(QW * 12 / 4); cvt_k<<<(n4 + 255) / 256, 256, 0, stream>>>(qkvw, wq, n4);
    n4 = (int)(OW * 12 / 4); cvt_k<<<(n4 + 255) / 256, 256, 0, stream>>>(outw, wo, n4);
    n4 = (int)(FW * 12 / 4); cvt_k<<<(n4 + 255) / 256, 256, 0, stream>>>(fcw,  wf, n4);
    n4 = (int)(PW * 12 / 4); cvt_k<<<(n4 + 255) / 256, 256, 0, stream>>>(prw,  wp, n4);
  }

  im2col_k<<<(NPATCH * 768) / 256, 256, 0, stream>>>(image, Ap);
  gemm_sw<0><<<8 * 13 * 3, 256, 0, stream>>>(Ap, cwb, nullptr, patch, nullptr, 768, 768, NPATCH, 13, 3, 49, 6);
  embed_ln_k<<<NTOK, 256, 0, stream>>>(patch, cls_emb, pos_emb, lnprew, lnpreb, x);

  for (int l = 0; l < 12; l++){
    const u16 *WQ, *WO, *WF, *WP;
    if (full){
      WQ = wq + (size_t)l * QW; WO = wo + (size_t)l * OW;
      WF = wf + (size_t)l * FW; WP = wp + (size_t)l * PW;
    } else {
      int n4;
      n4 = (int)(QW / 4); cvt_k<<<(n4 + 255) / 256, 256, 0, stream>>>(qkvw + (size_t)l * QW, sq_, n4);
      n4 = (int)(OW / 4); cvt_k<<<(n4 + 255) / 256, 256, 0, stream>>>(outw + (size_t)l * OW, so_, n4);
      n4 = (int)(FW / 4); cvt_k<<<(n4 + 255) / 256, 256, 0, stream>>>(fcw  + (size_t)l * FW, sf_, n4);
      n4 = (int)(PW / 4); cvt_k<<<(n4 + 255) / 256, 256, 0, stream>>>(prw  + (size_t)l * PW, sp_, n4);
      WQ = sq_; WO = so_; WF = sf_; WP = sp_;
    }
    ln_bf16_k<<<NTOK, 256, 0, stream>>>(x, ln1w + l * 768, ln1b + l * 768, h);
    // qkv: serial r6 kernel (KT=12), region 50x18 -> RM=13, RN=9
    gemm_sw<1><<<8 * 13 * 9, 256, 0, stream>>>(h, WQ, qkvb + l * 2304, nullptr, qkvB, 2304, 768, NTOK, 13, 9, 50, 18);
    // attn: 2 Q-half blocks per (b,h)
    attn_k<<<NB * NH * 2, 256, 0, stream>>>(qkvB, attno);
    // out: serial (KT=12), 50x6 -> RM=13, RN=3
    gemm_sw<2><<<8 * 13 * 3, 256, 0, stream>>>(attno, WO, outb + l * 768, x, nullptr, 768, 768, NTOK, 13, 3, 50, 6);
    ln_bf16_k<<<NTOK, 256, 0, stream>>>(x, ln2w + l * 768, ln2b + l * 768, h);
    // fc: serial (KT=12), 50x24 -> RM=13, RN=12
    gemm_sw<3><<<8 * 13 * 12, 256, 0, stream>>>(h, WF, fcb + l * 3072, nullptr, ffh, 3072, 768, NTOK, 13, 12, 50, 24);
    // pr: counted-vmcnt pipeline (KT=48), 50x6 -> RM=13, RN=3
    gemm_2ph<2><<<8 * 13 * 3, 256, 0, stream>>>(ffh, WP, prb + l * 768, x, nullptr, 768, 3072, NTOK, 13, 3, 50, 6);
  }

  ln_cls_k<<<NB, 256, 0, stream>>>(x, lnpostw, lnpostb, clsb);
  proj_k<<<(NB * 512) / 256, 256, 0, stream>>>(clsb, proj, feats);
  norm_k<<<NB, 256, 0, stream>>>(feats, (float*)d_out);
}

// Round 14
// 2734.532 us; speedup vs baseline: 1.3569x; 1.0211x over previous
//
#include <hip/hip_runtime.h>
#include <stdint.h>

#define SEQ 197
#define NB 32
#define NH 12
#define NTOK (SEQ*NB)      // 6304
#define MPAD 6400          // 50 * 128
#define NPATCH 6272        // 49 * 128

typedef unsigned short u16;
typedef unsigned int u32;
typedef __attribute__((ext_vector_type(8))) short bv8;    // 8 x bf16 (4 VGPR)
typedef __attribute__((ext_vector_type(4))) float f32x4;

__device__ __forceinline__ u16 f2bf(float f){
  u32 u = __float_as_uint(f);
  u = (u + 0x7fffu + ((u >> 16) & 1u)) >> 16;   // RNE
  return (u16)u;
}
__device__ __forceinline__ float bf2f(u16 h){ return __uint_as_float(((u32)h) << 16); }

#if defined(__has_builtin)
#if __has_builtin(__builtin_amdgcn_global_load_lds)
#define HAS_GLLDS 1
#endif
#endif

// async global->LDS, 16B per lane. LDS dest is wave-uniform base + lane*16.
__device__ __forceinline__ void gl_lds16(const void* g, void* l){
#ifdef HAS_GLLDS
  __builtin_amdgcn_global_load_lds(
      (const __attribute__((address_space(1))) void*)(uintptr_t)g,
      (__attribute__((address_space(3))) void*)(u32)(uintptr_t)l, 16, 0, 0);
#else
  int lane = threadIdx.x & 63;
  uint4 v = *(const uint4*)((const char*)g);
  *(uint4*)((char*)l + lane*16) = v;
#endif
}

// block-wide double reduction (blockDim.x == 256)
__device__ __forceinline__ void red2(float& a, float& b){
  #pragma unroll
  for (int o = 32; o > 0; o >>= 1){ a += __shfl_down(a, o); b += __shfl_down(b, o); }
  __shared__ float red[8];
  int w = threadIdx.x >> 6, ln = threadIdx.x & 63;
  if (ln == 0){ red[w] = a; red[4 + w] = b; }
  __syncthreads();
  a = red[0] + red[1] + red[2] + red[3];
  b = red[4] + red[5] + red[6] + red[7];
}

// ---------------- f32 -> bf16 weight conversion ----------------
__global__ __launch_bounds__(256) void cvt_k(const float* __restrict__ src, u16* __restrict__ dst, int n4){
  int i = blockIdx.x * 256 + threadIdx.x;
  if (i >= n4) return;
  float4 f = ((const float4*)src)[i];
  u32 lo = (u32)f2bf(f.x) | ((u32)f2bf(f.y) << 16);
  u32 hi = (u32)f2bf(f.z) | ((u32)f2bf(f.w) << 16);
  ((uint2*)dst)[i] = make_uint2(lo, hi);
}

// ---------------- im2col: image [32,3,224,224] -> A [6272, 768] bf16 ----------------
__global__ __launch_bounds__(256) void im2col_k(const float* __restrict__ img, u16* __restrict__ Ap){
  int gid = blockIdx.x * 256 + threadIdx.x;
  int row = gid / 768, k = gid - row * 768;
  int b = row / 196, p = row - b * 196;
  int pr = p / 14, pc = p - pr * 14;
  int c = k >> 8, r = k & 255;
  int ph = r >> 4, pw = r & 15;
  size_t src = ((size_t)(b * 3 + c) * 224 + (pr * 16 + ph)) * 224 + (pc * 16 + pw);
  Ap[gid] = f2bf(img[src]);
}

// ------------- GEMM 128x128 serial, r6-EXACT (best for KT=12) -------------
// EPI: 0 plain f32 | 1 +bias -> bf16 (LDS bounce) | 2 +bias, += Cf | 3 +bias GELU -> bf16 (LDS bounce)
template<int EPI>
__global__ __launch_bounds__(256, 2)
void gemm_sw(const u16* __restrict__ A, const u16* __restrict__ Bw,
             const float* __restrict__ bias, float* __restrict__ Cf,
             u16* __restrict__ Cb, int N, int K, int Mreal,
             int RM, int RN, int tmT, int tnT)
{
  __shared__ __align__(16) u16 sA[128 * 64];
  __shared__ __align__(16) u16 sB[128 * 64];
  const int xcd = blockIdx.x & 7, pos = blockIdx.x >> 3;
  const int xm = xcd >> 1, xn = xcd & 1;
  const int tm = xm * RM + pos / RN;
  const int tn = xn * RN + pos % RN;
  if (tm >= tmT || tn >= tnT) return;

  const int tid = threadIdx.x;
  const int lane = tid & 63, wave = tid >> 6;
  const int wm = wave >> 1, wn = wave & 1;      // 2x2 waves of 64x64
  const int lr = lane & 15, g = lane >> 4, g4 = g * 4;
  const int KT = K >> 6;

  const int srow = lane >> 3;
  const int sch = (lane & 7) ^ srow;
  const u16* aB[4]; const u16* bB[4];
  u16* lA[4]; u16* lB[4];
  #pragma unroll
  for (int j = 0; j < 4; j++){
    int rr = wave * 32 + j * 8;
    aB[j] = A  + (size_t)(tm * 128 + rr + srow) * K + sch * 8;
    bB[j] = Bw + (size_t)(tn * 128 + rr + srow) * K + sch * 8;
    lA[j] = sA + rr * 64;
    lB[j] = sB + rr * 64;
  }

  f32x4 acc[4][4] = {};

  for (int kt = 0; kt < KT; ++kt){
    __syncthreads();
    #pragma unroll
    for (int j = 0; j < 4; j++) gl_lds16(aB[j] + (size_t)kt * 64, lA[j]);
    #pragma unroll
    for (int j = 0; j < 4; j++) gl_lds16(bB[j] + (size_t)kt * 64, lB[j]);
    __syncthreads();
    #pragma unroll
    for (int kk = 0; kk < 2; kk++){
      bv8 af[4], bf[4];
      #pragma unroll
      for (int mi = 0; mi < 4; mi++){
        int row = wm * 64 + mi * 16 + lr;
        af[mi] = *(const bv8*)((const char*)sA + row * 128 + ((kk * 64 + g * 16) ^ ((row & 7) << 4)));
      }
      #pragma unroll
      for (int ni = 0; ni < 4; ni++){
        int row = wn * 64 + ni * 16 + lr;
        bf[ni] = *(const bv8*)((const char*)sB + row * 128 + ((kk * 64 + g * 16) ^ ((row & 7) << 4)));
      }
      #pragma unroll
      for (int mi = 0; mi < 4; mi++)
        #pragma unroll
        for (int ni = 0; ni < 4; ni++)
          acc[mi][ni] = __builtin_amdgcn_mfma_f32_16x16x32_bf16(af[mi], bf[ni], acc[mi][ni], 0, 0, 0);
    }
  }

  if (EPI == 1 || EPI == 3){
    __syncthreads();
    u16* sC = sA;
    #pragma unroll
    for (int mi = 0; mi < 4; mi++){
      #pragma unroll
      for (int ni = 0; ni < 4; ni++){
        int bcol = wn * 64 + ni * 16 + lr;
        float bvs = bias[tn * 128 + bcol];
        #pragma unroll
        for (int j = 0; j < 4; j++){
          int brow = wm * 64 + mi * 16 + g4 + j;
          float v = acc[mi][ni][j] + bvs;
          if (EPI == 3) v = 0.5f * v * (1.f + erff(v * 0.70710678118654752f));
          *(u16*)((char*)sC + brow * 256 + ((bcol * 2) ^ ((brow & 7) << 4))) = f2bf(v);
        }
      }
    }
    __syncthreads();
    #pragma unroll
    for (int c = 0; c < 8; c++){
      int off = c * 4096 + tid * 16;
      int row = off >> 8;
      int colb = off & 255;
      uint4 v = *(const uint4*)((const char*)sC + row * 256 + (colb ^ ((row & 7) << 4)));
      *(uint4*)((char*)(Cb + (size_t)(tm * 128 + row) * N + tn * 128) + colb) = v;
    }
  } else {
    #pragma unroll
    for (int ni = 0; ni < 4; ni++){
      int col = tn * 128 + wn * 64 + ni * 16 + lr;
      float bvs = (EPI != 0) ? bias[col] : 0.f;
      #pragma unroll
      for (int mi = 0; mi < 4; mi++){
        int row0 = tm * 128 + wm * 64 + mi * 16 + g4;
        #pragma unroll
        for (int j = 0; j < 4; j++){
          int row = row0 + j;
          if (row < Mreal){
            float v = acc[mi][ni][j] + bvs;
            size_t idx = (size_t)row * N + col;
            if (EPI == 0) Cf[idx] = v;
            else          Cf[idx] += v;
          }
        }
      }
    }
  }
}

// ------------- GEMM 128x128 2-phase counted-vmcnt, r7-EXACT: pr (KT=48) -------------
template<int EPI>
__global__ __launch_bounds__(256, 2)
void gemm_2ph(const u16* __restrict__ A, const u16* __restrict__ Bw,
              const float* __restrict__ bias, float* __restrict__ Cf,
              u16* __restrict__ Cb, int N, int K, int Mreal,
              int RM, int RN, int tmT, int tnT)
{
  __shared__ __align__(16) u16 sA0[128 * 64];
  __shared__ __align__(16) u16 sB0[128 * 64];
  __shared__ __align__(16) u16 sA1[128 * 64];
  __shared__ __align__(16) u16 sB1[128 * 64];
  const int xcd = blockIdx.x & 7, pos = blockIdx.x >> 3;
  const int xm = xcd >> 1, xn = xcd & 1;
  const int tm = xm * RM + pos / RN;
  const int tn = xn * RN + pos % RN;
  if (tm >= tmT || tn >= tnT) return;

  const int tid = threadIdx.x;
  const int lane = tid & 63, wave = tid >> 6;
  const int wm = wave >> 1, wn = wave & 1;
  const int lr = lane & 15, g = lane >> 4, g4 = g * 4;
  const int KT = K >> 6;

  const int srow = lane >> 3;
  const int sch = (lane & 7) ^ srow;
  const u16* aB[4]; const u16* bB[4];
  #pragma unroll
  for (int j = 0; j < 4; j++){
    int rr = wave * 32 + j * 8;
    aB[j] = A  + (size_t)(tm * 128 + rr + srow) * K + sch * 8;
    bB[j] = Bw + (size_t)(tn * 128 + rr + srow) * K + sch * 8;
  }

  f32x4 acc[4][4] = {};

  auto stage = [&](int kt, u16* dA, u16* dB){
    #pragma unroll
    for (int j = 0; j < 4; j++)
      gl_lds16(aB[j] + (size_t)kt * 64, dA + (wave * 32 + j * 8) * 64);
    #pragma unroll
    for (int j = 0; j < 4; j++)
      gl_lds16(bB[j] + (size_t)kt * 64, dB + (wave * 32 + j * 8) * 64);
  };
  auto tile = [&](const u16* sA, const u16* sB, u16* dA, u16* dB, int ktNext, bool doStage, bool last){
    if (last) asm volatile("s_waitcnt vmcnt(0)" ::: "memory");
    else      asm volatile("s_waitcnt vmcnt(8)" ::: "memory");
    __builtin_amdgcn_s_barrier();
    bv8 af[4][2], bf[4][2];
    #pragma unroll
    for (int mi = 0; mi < 4; mi++){
      int row = wm * 64 + mi * 16 + lr;
      #pragma unroll
      for (int kk = 0; kk < 2; kk++)
        af[mi][kk] = *(const bv8*)((const char*)sA + row * 128 + ((kk * 64 + g * 16) ^ ((row & 7) << 4)));
    }
    #pragma unroll
    for (int ni = 0; ni < 4; ni++){
      int row = wn * 64 + ni * 16 + lr;
      #pragma unroll
      for (int kk = 0; kk < 2; kk++)
        bf[ni][kk] = *(const bv8*)((const char*)sB + row * 128 + ((kk * 64 + g * 16) ^ ((row & 7) << 4)));
    }
    asm volatile("s_waitcnt lgkmcnt(0)" ::: "memory");
    __builtin_amdgcn_s_barrier();
    if (doStage) stage(ktNext, dA, dB);
    __builtin_amdgcn_s_setprio(1);
    #pragma unroll
    for (int kk = 0; kk < 2; kk++)
      #pragma unroll
      for (int mi = 0; mi < 4; mi++)
        #pragma unroll
        for (int ni = 0; ni < 4; ni++)
          acc[mi][ni] = __builtin_amdgcn_mfma_f32_16x16x32_bf16(af[mi][kk], bf[ni][kk], acc[mi][ni], 0, 0, 0);
    __builtin_amdgcn_s_setprio(0);
  };

  stage(0, sA0, sB0);
  stage(1, sA1, sB1);
  int t = 0;
  for (; t + 2 < KT; t += 2){
    tile(sA0, sB0, sA0, sB0, t + 2, true,  false);
    tile(sA1, sB1, sA1, sB1, t + 3, true,  false);
  }
  tile(sA0, sB0, sA0, sB0, 0, false, false);
  tile(sA1, sB1, sA1, sB1, 0, false, true);

  #pragma unroll
  for (int ni = 0; ni < 4; ni++){
    int col = tn * 128 + wn * 64 + ni * 16 + lr;
    float bvs = (EPI != 0) ? bias[col] : 0.f;
    #pragma unroll
    for (int mi = 0; mi < 4; mi++){
      int row0 = tm * 128 + wm * 64 + mi * 16 + g4;
      #pragma unroll
      for (int j = 0; j < 4; j++){
        int row = row0 + j;
        if (row < Mreal){
          float v = acc[mi][ni][j] + bvs;
          size_t idx = (size_t)row * N + col;
          if (EPI == 0) Cf[idx] = v;
          else          Cf[idx] += v;
        }
      }
    }
  }
}

// ---------------- MFMA flash attention: 2 blocks per (b,h), 4 waves x 32 Q-rows (r10-exact) ----------------
__global__ __launch_bounds__(256, 2) void attn_k(const u16* __restrict__ qkv, u16* __restrict__ o_out){
  __shared__ __align__(16) u16 sK[256 * 64];
  __shared__ __align__(16) u16 sVT[64 * 256];
  __shared__ __align__(16) u16 sP[4 * 32 * 64];
  const int bh2 = blockIdx.x;
  const int bh = bh2 >> 1, half = bh2 & 1;
  const int b = bh / NH, h = bh - b * NH;
  const int tid = threadIdx.x;
  const int lane = tid & 63, wave = tid >> 6;
  const int lr = lane & 15, g = lane >> 4;
  const int g4 = g * 4;
  const int wb = half * 128 + wave * 32;
  const u16* kbase = qkv + (size_t)b * SEQ * 2304 + h * 64 + 768;
  const u16* vbase = kbase + 768;

  bv8 qf[2][2];
  #pragma unroll
  for (int qt = 0; qt < 2; qt++){
    int q = wb + qt * 16 + lr; if (q > 196) q = 196;
    const u16* qr = qkv + (size_t)(b * SEQ + q) * 2304 + h * 64;
    #pragma unroll
    for (int kc = 0; kc < 2; kc++)
      qf[qt][kc] = *(const bv8*)(qr + kc * 32 + g * 8);
  }

  for (int i = tid; i < 197 * 32; i += 256){
    int r = i >> 5, c = i & 31;
    u32 kv_ = *(const u32*)(kbase + (size_t)r * 2304 + c * 2);
    *(u32*)((char*)sK + ((r * 128 + c * 4) ^ ((r & 7) << 4))) = kv_;
    u32 vv = *(const u32*)(vbase + (size_t)r * 2304 + c * 2);
    int hd0 = c * 2, hd1 = c * 2 + 1;
    *(u16*)((char*)sVT + ((hd0 * 512 + r * 2) ^ ((hd0 & 7) << 4))) = (u16)(vv & 0xffff);
    *(u16*)((char*)sVT + ((hd1 * 512 + r * 2) ^ ((hd1 & 7) << 4))) = (u16)(vv >> 16);
  }
  for (int i = tid; i < 59 * 32; i += 256){
    int r = 197 + (i >> 5), c = i & 31;
    *(u32*)((char*)sK + (r * 128 + c * 4)) = 0;
  }
  for (int i = tid; i < 59 * 64; i += 256){
    int kv = 197 + (i >> 6), hd = i & 63;
    *(u16*)((char*)sVT + ((hd * 512 + kv * 2) ^ ((hd & 7) << 4))) = 0;
  }
  __syncthreads();

  f32x4 acc_o[2][4] = {};
  float m_[2] = {-1e30f, -1e30f};
  float l_[2] = {0.f, 0.f};
  u16* sPw = sP + wave * 2048;

  for (int ch = 0; ch < 4; ++ch){
    f32x4 st[4][2] = {};
    #pragma unroll
    for (int kc = 0; kc < 2; kc++){
      bv8 kf[4];
      #pragma unroll
      for (int kvt = 0; kvt < 4; kvt++){
        int row = ch * 64 + kvt * 16 + lr;
        kf[kvt] = *(const bv8*)((const char*)sK + ((row * 128 + kc * 64 + g * 16) ^ ((row & 7) << 4)));
      }
      #pragma unroll
      for (int kvt = 0; kvt < 4; kvt++)
        #pragma unroll
        for (int qt = 0; qt < 2; qt++)
          st[kvt][qt] = __builtin_amdgcn_mfma_f32_16x16x32_bf16(kf[kvt], qf[qt][kc], st[kvt][qt], 0, 0, 0);
    }
    float fac[2];
    #pragma unroll
    for (int qt = 0; qt < 2; qt++){
      float mx = -1e30f;
      #pragma unroll
      for (int kvt = 0; kvt < 4; kvt++)
        #pragma unroll
        for (int j = 0; j < 4; j++){
          int kvg = ch * 64 + kvt * 16 + g4 + j;
          float s = st[kvt][qt][j] * 0.125f;
          s = (kvg < 197) ? s : -1e30f;
          st[kvt][qt][j] = s;
          mx = fmaxf(mx, s);
        }
      mx = fmaxf(mx, __shfl_xor(mx, 16));
      mx = fmaxf(mx, __shfl_xor(mx, 32));
      float nm = fmaxf(m_[qt], mx);
      fac[qt] = __expf(m_[qt] - nm);
      m_[qt] = nm;
      float ls = 0.f;
      #pragma unroll
      for (int kvt = 0; kvt < 4; kvt++)
        #pragma unroll
        for (int j = 0; j < 4; j++){
          float p = __expf(st[kvt][qt][j] - nm);
          st[kvt][qt][j] = p;
          ls += p;
        }
      ls += __shfl_xor(ls, 16);
      ls += __shfl_xor(ls, 32);
      l_[qt] = l_[qt] * fac[qt] + ls;
    }
    #pragma unroll
    for (int qt = 0; qt < 2; qt++)
      #pragma unroll
      for (int j = 0; j < 4; j++){
        float fj = __shfl(fac[qt], (lane & 48) | (g4 + j));
        #pragma unroll
        for (int nt = 0; nt < 4; nt++) acc_o[qt][nt][j] *= fj;
      }
    #pragma unroll
    for (int qt = 0; qt < 2; qt++){
      int row = qt * 16 + lr;
      #pragma unroll
      for (int kvt = 0; kvt < 4; kvt++){
        uint2 pk;
        pk.x = (u32)f2bf(st[kvt][qt][0]) | ((u32)f2bf(st[kvt][qt][1]) << 16);
        pk.y = (u32)f2bf(st[kvt][qt][2]) | ((u32)f2bf(st[kvt][qt][3]) << 16);
        *(uint2*)((char*)sPw + ((row * 128 + kvt * 32 + g * 8) ^ ((row & 7) << 4))) = pk;
      }
    }
    #pragma unroll
    for (int kc = 0; kc < 2; kc++){
      bv8 pa[2], vb[4];
      #pragma unroll
      for (int qt = 0; qt < 2; qt++){
        int row = qt * 16 + lr;
        pa[qt] = *(const bv8*)((const char*)sPw + ((row * 128 + kc * 64 + g * 16) ^ ((row & 7) << 4)));
      }
      #pragma unroll
      for (int nt = 0; nt < 4; nt++){
        int hd = nt * 16 + lr;
        vb[nt] = *(const bv8*)((const char*)sVT + ((hd * 512 + ch * 128 + kc * 64 + g * 16) ^ ((hd & 7) << 4)));
      }
      #pragma unroll
      for (int qt = 0; qt < 2; qt++)
        #pragma unroll
        for (int nt = 0; nt < 4; nt++)
          acc_o[qt][nt] = __builtin_amdgcn_mfma_f32_16x16x32_bf16(pa[qt], vb[nt], acc_o[qt][nt], 0, 0, 0);
    }
  }

  #pragma unroll
  for (int qt = 0; qt < 2; qt++)
    #pragma unroll
    for (int j = 0; j < 4; j++){
      float lj = __shfl(l_[qt], (lane & 48) | (g4 + j));
      float rl = 1.f / lj;
      int row = wb + qt * 16 + g4 + j;
      if (row < 197){
        u16* dst = o_out + (size_t)(b * SEQ + row) * 768 + h * 64;
        #pragma unroll
        for (int nt = 0; nt < 4; nt++)
          dst[nt * 16 + lr] = f2bf(acc_o[qt][nt][j] * rl);
      }
    }
}

// ---------------- embed (cls + patches + pos) then ln_pre -> x f32 ----------------
__global__ __launch_bounds__(256) void embed_ln_k(const float* __restrict__ patch, const float* __restrict__ cls,
    const float* __restrict__ pos, const float* __restrict__ w, const float* __restrict__ bb, float* __restrict__ x)
{
  int t = blockIdx.x;
  int b = t / SEQ, s = t - b * SEQ;
  int tid = threadIdx.x;
  float v[3];
  #pragma unroll
  for (int i = 0; i < 3; i++){
    int d = tid + i * 256;
    float base = (s == 0) ? cls[d] : patch[(size_t)(b * 196 + s - 1) * 768 + d];
    v[i] = base + pos[s * 768 + d];
  }
  float sm = v[0] + v[1] + v[2];
  float sq = v[0]*v[0] + v[1]*v[1] + v[2]*v[2];
  red2(sm, sq);
  float m = sm * (1.f / 768.f);
  float rs = rsqrtf(sq * (1.f / 768.f) - m * m + 1e-5f);
  #pragma unroll
  for (int i = 0; i < 3; i++){
    int d = tid + i * 256;
    x[(size_t)t * 768 + d] = (v[i] - m) * rs * w[d] + bb[d];
  }
}

// ---------------- LN (f32 in) -> bf16 out ----------------
__global__ __launch_bounds__(256) void ln_bf16_k(const float* __restrict__ x, const float* __restrict__ w,
    const float* __restrict__ bb, u16* __restrict__ h)
{
  int t = blockIdx.x, tid = threadIdx.x;
  const float* xr = x + (size_t)t * 768;
  float v[3];
  #pragma unroll
  for (int i = 0; i < 3; i++) v[i] = xr[tid + i * 256];
  float sm = v[0] + v[1] + v[2];
  float sq = v[0]*v[0] + v[1]*v[1] + v[2]*v[2];
  red2(sm, sq);
  float m = sm * (1.f / 768.f);
  float rs = rsqrtf(sq * (1.f / 768.f) - m * m + 1e-5f);
  #pragma unroll
  for (int i = 0; i < 3; i++){
    int d = tid + i * 256;
    h[(size_t)t * 768 + d] = f2bf((v[i] - m) * rs * w[d] + bb[d]);
  }
}

// ---------------- ln_post on cls tokens -> f32 ----------------
__global__ __launch_bounds__(256) void ln_cls_k(const float* __restrict__ x, const float* __restrict__ w,
    const float* __restrict__ bb, float* __restrict__ cls)
{
  int b = blockIdx.x, tid = threadIdx.x;
  const float* xr = x + (size_t)b * SEQ * 768;
  float v[3];
  #pragma unroll
  for (int i = 0; i < 3; i++) v[i] = xr[tid + i * 256];
  float sm = v[0] + v[1] + v[2];
  float sq = v[0]*v[0] + v[1]*v[1] + v[2]*v[2];
  red2(sm, sq);
  float m = sm * (1.f / 768.f);
  float rs = rsqrtf(sq * (1.f / 768.f) - m * m + 1e-5f);
  #pragma unroll
  for (int i = 0; i < 3; i++){
    int d = tid + i * 256;
    cls[b * 768 + d] = (v[i] - m) * rs * w[d] + bb[d];
  }
}

// ---------------- final projection [32,768] @ [768,512] ----------------
__global__ __launch_bounds__(256) void proj_k(const float* __restrict__ cls, const float* __restrict__ P,
                                              float* __restrict__ feats){
  int gid = blockIdx.x * 256 + threadIdx.x;
  int b = gid >> 9, e = gid & 511;
  const float* c = cls + b * 768;
  float a0 = 0, a1 = 0, a2 = 0, a3 = 0;
  for (int d = 0; d < 768; d += 4){
    a0 += c[d]     * P[(size_t)d * 512 + e];
    a1 += c[d + 1] * P[(size_t)(d + 1) * 512 + e];
    a2 += c[d + 2] * P[(size_t)(d + 2) * 512 + e];
    a3 += c[d + 3] * P[(size_t)(d + 3) * 512 + e];
  }
  feats[gid] = (a0 + a1) + (a2 + a3);
}

// ---------------- L2 normalize ----------------
__global__ __launch_bounds__(256) void norm_k(const float* __restrict__ feats, float* __restrict__ out){
  int b = blockIdx.x, tid = threadIdx.x;
  float v0 = feats[b * 512 + tid], v1 = feats[b * 512 + 256 + tid];
  float sq = v0 * v0 + v1 * v1, dummy = 0.f;
  red2(sq, dummy);
  float inv = 1.f / sqrtf(sq);
  out[b * 512 + tid] = v0 * inv;
  out[b * 512 + 256 + tid] = v1 * inv;
}

extern "C" void kernel_launch(void* const* d_in, const int* in_sizes, int n_in,
                              void* d_out, int out_size, void* d_ws, size_t ws_size,
                              hipStream_t stream)
{
  const float* image   = (const float*)d_in[0];
  const float* conv_w  = (const float*)d_in[1];
  const float* cls_emb = (const float*)d_in[2];
  const float* pos_emb = (const float*)d_in[3];
  const float* lnprew  = (const float*)d_in[4];
  const float* lnpreb  = (const float*)d_in[5];
  const float* ln1w    = (const float*)d_in[6];
  const float* ln1b    = (const float*)d_in[7];
  const float* qkvw    = (const float*)d_in[8];
  const float* qkvb    = (const float*)d_in[9];
  const float* outw    = (const float*)d_in[10];
  const float* outb    = (const float*)d_in[11];
  const float* ln2w    = (const float*)d_in[12];
  const float* ln2b    = (const float*)d_in[13];
  const float* fcw     = (const float*)d_in[14];
  const float* fcb     = (const float*)d_in[15];
  const float* prw     = (const float*)d_in[16];
  const float* prb     = (const float*)d_in[17];
  const float* lnpostw = (const float*)d_in[18];
  const float* lnpostb = (const float*)d_in[19];
  const float* proj    = (const float*)d_in[20];
  (void)in_sizes; (void)n_in; (void)out_size;

  const size_t QW = (size_t)2304 * 768, OW = (size_t)768 * 768;
  const size_t FW = (size_t)3072 * 768, PW = (size_t)768 * 3072;
  const size_t CW = (size_t)768 * 768;

  char* p = (char*)d_ws;
  auto alloc = [&](size_t bytes)->char*{ char* r = p; p += (bytes + 255) & ~(size_t)255; return r; };
  float* x     = (float*)alloc((size_t)MPAD * 768 * 4);
  u16*   h     = (u16*)  alloc((size_t)MPAD * 768 * 2);
  u16*   qkvB  = (u16*)  alloc((size_t)MPAD * 2304 * 2);
  u16*   attno = (u16*)  alloc((size_t)MPAD * 768 * 2);
  u16*   ffh   = (u16*)  alloc((size_t)MPAD * 3072 * 2);
  u16*   Ap    = (u16*)  alloc((size_t)NPATCH * 768 * 2);
  float* patch = (float*)alloc((size_t)NPATCH * 768 * 4);
  float* clsb  = (float*)alloc((size_t)32 * 768 * 4);
  float* feats = (float*)alloc((size_t)32 * 512 * 4);
  u16*   cwb   = (u16*)  alloc(CW * 2);
  size_t base_used = (size_t)(p - (char*)d_ws);
  size_t full_need = (QW + OW + FW + PW) * 12 * 2;
  bool full = (base_used + full_need + 4096 <= ws_size);

  u16 *wq = nullptr, *wo = nullptr, *wf = nullptr, *wp = nullptr;
  u16 *sq_ = nullptr, *so_ = nullptr, *sf_ = nullptr, *sp_ = nullptr;
  if (full){
    wq = (u16*)alloc(QW * 12 * 2); wo = (u16*)alloc(OW * 12 * 2);
    wf = (u16*)alloc(FW * 12 * 2); wp = (u16*)alloc(PW * 12 * 2);
  } else {
    sq_ = (u16*)alloc(QW * 2); so_ = (u16*)alloc(OW * 2);
    sf_ = (u16*)alloc(FW * 2); sp_ = (u16*)alloc(PW * 2);
  }
  if ((size_t)(p - (char*)d_ws) > ws_size) return;

  { int n4 = (int)(CW / 4); cvt_k<<<(n4 + 255) / 256, 256, 0, stream>>>(conv_w, cwb, n4); }
  if (full){
    int n4;
    n4 = (int)(QW * 12 / 4); cvt_k<<<(n4 + 255) / 256, 256, 0, stream>>>(qkvw, wq, n4);
    n4 = (int)(OW * 12 / 4); cvt_k<<<(n4 + 255) / 256, 256, 0, stream>>>(outw, wo, n4);
    n4 = (int)(FW * 12 / 4); cvt_k<<<(n4 + 255) / 256, 256, 0, stream>>>(fcw,  wf, n4);
    n4 = (int)(PW * 12 / 4); cvt_k<<<(n4 + 255) / 256, 256, 0, stream>>>(prw,  wp, n4);
  }

  im2col_k<<<(NPATCH * 768) / 256, 256, 0, stream>>>(image, Ap);
  gemm_sw<0><<<8 * 13 * 3, 256, 0, stream>>>(Ap, cwb, nullptr, patch, nullptr, 768, 768, NPATCH, 13, 3, 49, 6);
  embed_ln_k<<<NTOK, 256, 0, stream>>>(patch, cls_emb, pos_emb, lnprew, lnpreb, x);

  for (int l = 0; l < 12; l++){
    const u16 *WQ, *WO, *WF, *WP;
    if (full){
      WQ = wq + (size_t)l * QW; WO = wo + (size_t)l * OW;
      WF = wf + (size_t)l * FW; WP = wp + (size_t)l * PW;
    } else {
      int n4;
      n4 = (int)(QW / 4); cvt_k<<<(n4 + 255) / 256, 256, 0, stream>>>(qkvw + (size_t)l * QW, sq_, n4);
      n4 = (int)(OW / 4); cvt_k<<<(n4 + 255) / 256, 256, 0, stream>>>(outw + (size_t)l * OW, so_, n4);
      n4 = (int)(FW / 4); cvt_k<<<(n4 + 255) / 256, 256, 0, stream>>>(fcw  + (size_t)l * FW, sf_, n4);
      n4 = (int)(PW / 4); cvt_k<<<(n4 + 255) / 256, 256, 0, stream>>>(prw  + (size_t)l * PW, sp_, n4);
      WQ = sq_; WO = so_; WF = sf_; WP = sp_;
    }
    ln_bf16_k<<<NTOK, 256, 0, stream>>>(x, ln1w + l * 768, ln1b + l * 768, h);
    // qkv: serial r6 kernel (KT=12), region 50x18 -> RM=13, RN=9
    gemm_sw<1><<<8 * 13 * 9, 256, 0, stream>>>(h, WQ, qkvb + l * 2304, nullptr, qkvB, 2304, 768, NTOK, 13, 9, 50, 18);
    // attn: 2 Q-half blocks per (b,h)
    attn_k<<<NB * NH * 2, 256, 0, stream>>>(qkvB, attno);
    // out: serial (KT=12), 50x6 -> RM=13, RN=3
    gemm_sw<2><<<8 * 13 * 3, 256, 0, stream>>>(attno, WO, outb + l * 768, x, nullptr, 768, 768, NTOK, 13, 3, 50, 6);
    ln_bf16_k<<<NTOK, 256, 0, stream>>>(x, ln2w + l * 768, ln2b + l * 768, h);
    // fc: serial (KT=12), 50x24 -> RM=13, RN=12
    gemm_sw<3><<<8 * 13 * 12, 256, 0, stream>>>(h, WF, fcb + l * 3072, nullptr, ffh, 3072, 768, NTOK, 13, 12, 50, 24);
    // pr: counted-vmcnt pipeline (KT=48), 50x6 -> RM=13, RN=3
    gemm_2ph<2><<<8 * 13 * 3, 256, 0, stream>>>(ffh, WP, prb + l * 768, x, nullptr, 768, 3072, NTOK, 13, 3, 50, 6);
  }

  ln_cls_k<<<NB, 256, 0, stream>>>(x, lnpostw, lnpostb, clsb);
  proj_k<<<(NB * 512) / 256, 256, 0, stream>>>(clsb, proj, feats);
  norm_k<<<NB, 256, 0, stream>>>(feats, (float*)d_out);
}